// Round 10
// baseline (1366.528 us; speedup 1.0000x reference)
//
#include <hip/hip_runtime.h>

// Shapes (fixed by the problem)
#define BB 16
#define EE 1024
#define NN 2048
#define DD 256
#define LL 3

typedef _Float16 half8 __attribute__((ext_vector_type(8)));
typedef _Float16 half4 __attribute__((ext_vector_type(4)));
typedef _Float16 half2_t __attribute__((ext_vector_type(2)));
typedef float f32x4 __attribute__((ext_vector_type(4)));

// online-softmax pair merge: (m,s) <- (m,s) + (m2,s2)
__device__ __forceinline__ void pmerge(float& m, float& s, float m2, float s2) {
    float nm = fmaxf(m, m2);
    s = s * __expf(m - nm) + s2 * __expf(m2 - nm);
    m = nm;
}

__device__ __forceinline__ unsigned pk2(_Float16 a, _Float16 b) {
    union { _Float16 h[2]; unsigned u; } x;
    x.h[0] = a; x.h[1] = b;
    return x.u;
}

// ---------------------------------------------------------------------------
// Raw barriers WITHOUT the vmcnt(0) drain __syncthreads carries (T4).
// __syncthreads makes hipcc emit `s_waitcnt vmcnt(0) lgkmcnt(0)` before
// s_barrier, force-draining in-flight register prefetch loads at EVERY
// barrier — which made prefetch depth irrelevant (R3/R5 nulls). Barriers
// only need LDS ordering:
//  bar_entry : prior LDS reads are retired in program order (their MFMA
//              consumers already waited lgkmcnt) -> bare s_barrier; the
//              trailing memory-clobber asm stops the upcoming ds_writes
//              from being hoisted above the barrier.
//  bar_commit: this wave's ds_writes complete (lgkmcnt(0)) before the
//              barrier so they are visible to all waves after it.
__device__ __forceinline__ void bar_entry() {
    __builtin_amdgcn_s_barrier();
    asm volatile("" ::: "memory");
}
__device__ __forceinline__ void bar_commit() {
    asm volatile("s_waitcnt lgkmcnt(0)" ::: "memory");
    __builtin_amdgcn_s_barrier();
}

// ---------------------------------------------------------------------------
// f32 -> (hi, lo) f16 split cast: x = hi + lo, hi = f16(x), lo = f16(x - hi)
__global__ void split_cast(const float* __restrict__ in, _Float16* __restrict__ hi,
                           _Float16* __restrict__ lo, size_t n) {
    size_t stride = (size_t)gridDim.x * blockDim.x * 4;
    for (size_t i = ((size_t)blockIdx.x * blockDim.x + threadIdx.x) * 4; i < n; i += stride) {
        float4 v = *(const float4*)&in[i];
        half4 hh, ll;
        _Float16 h;
        h = (_Float16)v.x; hh[0] = h; ll[0] = (_Float16)(v.x - (float)h);
        h = (_Float16)v.y; hh[1] = h; ll[1] = (_Float16)(v.y - (float)h);
        h = (_Float16)v.z; hh[2] = h; ll[2] = (_Float16)(v.z - (float)h);
        h = (_Float16)v.w; hh[3] = h; ll[3] = (_Float16)(v.w - (float)h);
        *(half4*)&hi[i] = hh;
        *(half4*)&lo[i] = ll;
    }
}

// f32 (exact 0/1) -> u8
__global__ void cast_u8(const float* __restrict__ in, unsigned char* __restrict__ out, size_t n) {
    size_t stride = (size_t)gridDim.x * blockDim.x * 4;
    for (size_t i = ((size_t)blockIdx.x * blockDim.x + threadIdx.x) * 4; i < n; i += stride) {
        float4 v = *(const float4*)&in[i];
        unsigned int pack = (unsigned int)(unsigned char)v.x |
                            ((unsigned int)(unsigned char)v.y << 8) |
                            ((unsigned int)(unsigned char)v.z << 16) |
                            ((unsigned int)(unsigned char)v.w << 24);
        *(unsigned int*)&out[i] = pack;
    }
}

// ---------------------------------------------------------------------------
// per-batch transpose + split cast: in [R,C] f32 -> oh/ol [C,R] f16
__global__ void transpose_split(const float* __restrict__ in, _Float16* __restrict__ oh,
                                _Float16* __restrict__ olo, int R, int C) {
    int b = blockIdx.z;
    int c0 = blockIdx.x * 64, r0 = blockIdx.y * 64;
    const float* ib = in + (size_t)b * R * C;
    size_t ob = (size_t)b * R * C;
    __shared__ float tile[64][65];
    int t = threadIdx.x;
    int cl = t & 63, rb = t >> 6;
#pragma unroll
    for (int j = 0; j < 16; j++) {
        int rl = rb + j * 4;
        tile[rl][cl] = ib[(size_t)(r0 + rl) * C + c0 + cl];
    }
    __syncthreads();
    int oc = t >> 2, q = t & 3;
    half8 h0, h1, l0, l1;
#pragma unroll
    for (int i = 0; i < 8; i++) {
        float v = tile[q * 16 + i][oc];
        _Float16 h = (_Float16)v;
        h0[i] = h; l0[i] = (_Float16)(v - (float)h);
    }
#pragma unroll
    for (int i = 0; i < 8; i++) {
        float v = tile[q * 16 + 8 + i][oc];
        _Float16 h = (_Float16)v;
        h1[i] = h; l1[i] = (_Float16)(v - (float)h);
    }
    size_t o = ob + (size_t)(c0 + oc) * R + r0 + q * 16;
    *(half8*)&oh[o] = h0; *(half8*)&oh[o + 8] = h1;
    *(half8*)&olo[o] = l0; *(half8*)&olo[o + 8] = l1;
}

// transpose + split cast with e-pair PERMUTATION within each 32-block of R:
// out position (within 32-group) 2x holds e-local x, 2x+1 holds x+16.
// Matches fused_agg<true>'s A-LDS k-slot order so A and B share one k-perm.
__global__ void transpose_split_perm(const float* __restrict__ in, _Float16* __restrict__ oh,
                                     _Float16* __restrict__ olo, int R, int C) {
    int b = blockIdx.z;
    int c0 = blockIdx.x * 64, r0 = blockIdx.y * 64;
    const float* ib = in + (size_t)b * R * C;
    size_t ob = (size_t)b * R * C;
    __shared__ float tile[64][65];
    int t = threadIdx.x;
    int cl = t & 63, rb = t >> 6;
#pragma unroll
    for (int j = 0; j < 16; j++) {
        int rl = rb + j * 4;
        tile[rl][cl] = ib[(size_t)(r0 + rl) * C + c0 + cl];
    }
    __syncthreads();
    int oc = t >> 2, q = t & 3;
    int g = q >> 1, sub = q & 1;
#pragma unroll
    for (int j = 0; j < 8; j++) {
        int x = sub * 8 + j;
        float v1 = tile[g * 32 + x][oc];
        float v2 = tile[g * 32 + x + 16][oc];
        _Float16 a = (_Float16)v1, b2 = (_Float16)v2;
        _Float16 la = (_Float16)(v1 - (float)a), lb = (_Float16)(v2 - (float)b2);
        size_t o = ob + (size_t)(c0 + oc) * R + r0 + g * 32 + 2 * x;
        half2_t hp; hp[0] = a; hp[1] = b2;
        half2_t lp; lp[0] = la; lp[1] = lb;
        *(half2_t*)&oh[o] = hp;
        *(half2_t*)&olo[o] = lp;
    }
}

// per-batch transpose: in [R,C] f32 (exact 0/1) -> out [C,R] u8
__global__ void transpose_u8(const float* __restrict__ in, unsigned char* __restrict__ out,
                             int R, int C) {
    int b = blockIdx.z;
    int c0 = blockIdx.x * 64, r0 = blockIdx.y * 64;
    const float* ib = in + (size_t)b * R * C;
    unsigned char* ob = out + (size_t)b * R * C;
    __shared__ float tile[64][65];
    int t = threadIdx.x;
    int cl = t & 63, rb = t >> 6;
#pragma unroll
    for (int j = 0; j < 16; j++) {
        int rl = rb + j * 4;
        tile[rl][cl] = ib[(size_t)(r0 + rl) * C + c0 + cl];
    }
    __syncthreads();
    int oc = t >> 2, q = t & 3;
    union { unsigned char b[16]; uint4 v; } u;
#pragma unroll
    for (int i = 0; i < 16; i++) u.b[i] = (unsigned char)tile[q * 16 + i][oc];
    size_t o = (size_t)(c0 + oc) * R + r0 + q * 16;
    *(uint4*)&ob[o] = u.v;
}

// ---------------------------------------------------------------------------
// NT GEMM with split-f16 emulated-fp32 operands (3 passes: hh + hl + lh).
// R10: __syncthreads -> bar_entry/bar_commit so the register prefetch for
// kt+1 is no longer force-drained at each barrier (counted vmcnt at use).
template <bool A_SPLIT, bool B_SPLIT, bool HAS_BIAS, bool RELU, bool HAS_ADD,
          bool WRITE_F32, bool WRITE_SPLIT, bool B_BATCHED>
__global__ __launch_bounds__(256) void gemm_nt(
    const _Float16* __restrict__ Ah, const _Float16* __restrict__ Al,
    const _Float16* __restrict__ Bh, const _Float16* __restrict__ Bl,
    const float* __restrict__ bias, float bscale,
    const float* __restrict__ addsrc,
    float* __restrict__ Cf, _Float16* __restrict__ Chi, _Float16* __restrict__ Clo,
    int M, int Nn, int K) {
    const int bz = blockIdx.z;
    const int m0 = blockIdx.x * 128, n0 = blockIdx.y * 128;
    const int t = threadIdx.x, lane = t & 63, wid = t >> 6;
    const int wm = wid >> 1, wn = wid & 1;
    const size_t offA = (size_t)bz * M * K;
    const size_t offB = B_BATCHED ? (size_t)bz * Nn * K : (size_t)0;
    const _Float16* Abh = Ah + offA;
    const _Float16* Abl = A_SPLIT ? (Al + offA) : nullptr;
    const _Float16* Bbh = Bh + offB;
    const _Float16* Bbl = B_SPLIT ? (Bl + offB) : nullptr;

    __shared__ _Float16 sAh[128 * 32];
    __shared__ _Float16 sBh[128 * 32];
    __shared__ _Float16 sAl[A_SPLIT ? 128 * 32 : 1];
    __shared__ _Float16 sBl[B_SPLIT ? 128 * 32 : 1];

    f32x4 acc[4][4] = {};
    const int nk = K >> 5;

    auto gA = [&](const _Float16* base, int kt, int q) {
        return *(const uint4*)(base + (size_t)(m0 + (q >> 2)) * K + (kt << 5) + ((q & 3) << 3));
    };
    auto gB = [&](const _Float16* base, int kt, int q) {
        return *(const uint4*)(base + (size_t)(n0 + (q >> 2)) * K + (kt << 5) + ((q & 3) << 3));
    };

    uint4 rah0 = gA(Abh, 0, t), rah1 = gA(Abh, 0, t + 256);
    uint4 rbh0 = gB(Bbh, 0, t), rbh1 = gB(Bbh, 0, t + 256);
    uint4 ral0 = {}, ral1 = {}, rbl0 = {}, rbl1 = {};
    if (A_SPLIT) { ral0 = gA(Abl, 0, t); ral1 = gA(Abl, 0, t + 256); }
    if (B_SPLIT) { rbl0 = gB(Bbl, 0, t); rbl1 = gB(Bbl, 0, t + 256); }

    for (int kt = 0; kt < nk; ++kt) {
        bar_entry();
        ((uint4*)sAh)[t] = rah0; ((uint4*)sAh)[t + 256] = rah1;
        ((uint4*)sBh)[t] = rbh0; ((uint4*)sBh)[t + 256] = rbh1;
        if (A_SPLIT) { ((uint4*)sAl)[t] = ral0; ((uint4*)sAl)[t + 256] = ral1; }
        if (B_SPLIT) { ((uint4*)sBl)[t] = rbl0; ((uint4*)sBl)[t + 256] = rbl1; }
        bar_commit();
        if (kt + 1 < nk) {
            rah0 = gA(Abh, kt + 1, t); rah1 = gA(Abh, kt + 1, t + 256);
            rbh0 = gB(Bbh, kt + 1, t); rbh1 = gB(Bbh, kt + 1, t + 256);
            if (A_SPLIT) { ral0 = gA(Abl, kt + 1, t); ral1 = gA(Abl, kt + 1, t + 256); }
            if (B_SPLIT) { rbl0 = gB(Bbl, kt + 1, t); rbl1 = gB(Bbl, kt + 1, t + 256); }
        }
        half8 afh[4], bfh[4], afl[4], bfl[4];
#pragma unroll
        for (int mi = 0; mi < 4; mi++) {
            int off = (wm * 64 + mi * 16 + (lane & 15)) * 32 + ((lane >> 4) << 3);
            afh[mi] = *(const half8*)&sAh[off];
            if (A_SPLIT) afl[mi] = *(const half8*)&sAl[off];
        }
#pragma unroll
        for (int nj = 0; nj < 4; nj++) {
            int off = (wn * 64 + nj * 16 + (lane & 15)) * 32 + ((lane >> 4) << 3);
            bfh[nj] = *(const half8*)&sBh[off];
            if (B_SPLIT) bfl[nj] = *(const half8*)&sBl[off];
        }
#pragma unroll
        for (int mi = 0; mi < 4; mi++)
#pragma unroll
            for (int nj = 0; nj < 4; nj++) {
                acc[mi][nj] = __builtin_amdgcn_mfma_f32_16x16x32_f16(afh[mi], bfh[nj], acc[mi][nj], 0, 0, 0);
                if (B_SPLIT)
                    acc[mi][nj] = __builtin_amdgcn_mfma_f32_16x16x32_f16(afh[mi], bfl[nj], acc[mi][nj], 0, 0, 0);
                if (A_SPLIT)
                    acc[mi][nj] = __builtin_amdgcn_mfma_f32_16x16x32_f16(afl[mi], bfh[nj], acc[mi][nj], 0, 0, 0);
            }
    }

    const int rbase = (lane >> 4) * 4, cc = lane & 15;
#pragma unroll
    for (int mi = 0; mi < 4; mi++) {
#pragma unroll
        for (int nj = 0; nj < 4; nj++) {
            int gn = n0 + wn * 64 + nj * 16 + cc;
            float bv = HAS_BIAS ? bias[gn] * bscale : 0.f;
#pragma unroll
            for (int r = 0; r < 4; r++) {
                int gm = m0 + wm * 64 + mi * 16 + rbase + r;
                float v = acc[mi][nj][r];
                if (HAS_BIAS) v += bv;
                size_t off = ((size_t)bz * M + gm) * Nn + gn;
                if (HAS_ADD) v += addsrc[off];
                if (RELU) v = fmaxf(v, 0.f);
                if (WRITE_F32) Cf[off] = v;
                if (WRITE_SPLIT) {
                    _Float16 h = (_Float16)v;
                    Chi[off] = h;
                    Clo[off] = (_Float16)(v - (float)h);
                }
            }
        }
    }
}

// ---------------------------------------------------------------------------
// FUSED normalize + aggregation GEMM:
//   X[b][m][d] = (softmax-normalized P)[m][k] @ B[d][k]^T + addsrc, split-f16 out
// A-tile is computed on the fly from S + mask + per-m stats (c = max+ln(sum)):
//   P[m][k] = msk ? exp(s - c[m]) : exp(-c[m])
// TRANSA=true  (agg1): transposed staging + e-pair k-perm + XOR swizzle.
// TRANSA=false (agg2): direct row-major staging.
// 64x128 tile, BK=32, 256 threads, 2x2 waves, wave tile 32x64 (champion
// geometry). R10 change: (a) R5's correctness-verified 2-deep RAW A
// prefetch (pure loads, exp deferred to store time); (b) raw barriers
// (bar_entry/bar_commit) replace __syncthreads so those loads are no
// longer vmcnt(0)-drained at each barrier — counted vmcnt at consumption,
// ~2 compute phases + 2 barriers of cover. This is the T4 mechanism that
// explains why R3/R5 prefetch depth was measured neutral.
template <bool TRANSA>
__global__ __launch_bounds__(256) void fused_agg(
    const float* __restrict__ S_, const unsigned char* __restrict__ Mk,
    const float2* __restrict__ st, const _Float16* __restrict__ Bh,
    const _Float16* __restrict__ Bl, const float* __restrict__ addsrc,
    _Float16* __restrict__ Xhi, _Float16* __restrict__ Xlo,
    int M, int K) {
    const int bz = blockIdx.z;
    const int m0 = blockIdx.x * 64, n0 = blockIdx.y * 128;
    const int t = threadIdx.x, lane = t & 63, wid = t >> 6;
    const int wm = wid >> 1, wn = wid & 1;   // 2x2 waves; wave tile 32(m) x 64(n)
    const float* Sb = S_ + (size_t)bz * EE * NN;
    const unsigned char* Mb = Mk + (size_t)bz * EE * NN;
    const float2* stb = st + (size_t)bz * M;
    const _Float16* Bbh = Bh + (size_t)bz * DD * K;
    const _Float16* Bbl = Bl + (size_t)bz * DD * K;

    __shared__ _Float16 sA[64 * 32];
    __shared__ _Float16 sBh[128 * 32];
    __shared__ _Float16 sBl[128 * 32];

    f32x4 acc[2][4] = {};
    const int nk = K >> 5;   // 32 (agg1) or 64 (agg2) — always even

    // hoisted per-thread softmax stats (c, e^-c)
    float stc[4], stem[4];
    if (TRANSA) {
        int ncol = (t & 15) * 4;
#pragma unroll
        for (int i = 0; i < 4; i++) {
            float2 v = stb[m0 + ncol + i];
            stc[i] = v.x; stem[i] = v.y;
        }
    } else {
#pragma unroll
        for (int p = 0; p < 2; p++) {
            float2 v = stb[m0 + (t >> 3) + p * 32];
            stc[p] = v.x; stem[p] = v.y;
        }
    }

    // raw A prefetch sets (pure loads; exp/pack deferred to store time)
    struct RawA { f32x4 s1, s2; unsigned a1, a2; };
    RawA A0, A1;
    uint4 rbh0, rbh1, rbl0, rbl1;

    auto prefA_load = [&](RawA& R, int kt) {
        if (TRANSA) {
            // k-tile = 32 e-rows (pairs r, r+16), m-tile = 64 n-cols
            int r = t >> 4, ncol = (t & 15) * 4;
            size_t rowoff = (size_t)(kt * 32 + r) * NN + m0 + ncol;
            R.s1 = *(const f32x4*)(Sb + rowoff);
            R.s2 = *(const f32x4*)(Sb + rowoff + (size_t)16 * NN);
            R.a1 = *(const unsigned*)(Mb + rowoff);
            R.a2 = *(const unsigned*)(Mb + rowoff + (size_t)16 * NN);
        } else {
            int kc = (t & 7) * 4, rb = t >> 3;   // rows rb and rb+32
            size_t ro1 = (size_t)(m0 + rb) * NN + kt * 32 + kc;
            size_t ro2 = (size_t)(m0 + rb + 32) * NN + kt * 32 + kc;
            R.s1 = *(const f32x4*)(Sb + ro1);
            R.s2 = *(const f32x4*)(Sb + ro2);
            R.a1 = *(const unsigned*)(Mb + ro1);
            R.a2 = *(const unsigned*)(Mb + ro2);
        }
    };
    auto prefB = [&](int kt) {
        auto g = [&](const _Float16* base, int q) {
            return *(const uint4*)(base + (size_t)(n0 + (q >> 2)) * K + kt * 32 + (q & 3) * 8);
        };
        rbh0 = g(Bbh, t); rbh1 = g(Bbh, t + 256);
        rbl0 = g(Bbl, t); rbl1 = g(Bbl, t + 256);
    };
    auto storeA = [&](RawA& R) {
        if (TRANSA) {
            int r = t >> 4, ncol = (t & 15) * 4;
#pragma unroll
            for (int i = 0; i < 4; i++) {
                float c = stc[i], em = stem[i];
                float x1 = ((R.a1 >> (8 * i)) & 255u) ? __expf(R.s1[i] - c) : em;
                float x2 = ((R.a2 >> (8 * i)) & 255u) ? __expf(R.s2[i] - c) : em;
                int n = ncol + i;
                int cp = (r >> 2) ^ ((n >> 2) & 3);
                ((unsigned*)sA)[n * 16 + cp * 4 + (r & 3)] = pk2((_Float16)x1, (_Float16)x2);
            }
        } else {
            int kc = (t & 7) * 4, rb = t >> 3;
            {
                float c = stc[0], em = stem[0];
                _Float16 h0 = (_Float16)(((R.a1) & 255u) ? __expf(R.s1[0] - c) : em);
                _Float16 h1 = (_Float16)(((R.a1 >> 8) & 255u) ? __expf(R.s1[1] - c) : em);
                _Float16 h2 = (_Float16)(((R.a1 >> 16) & 255u) ? __expf(R.s1[2] - c) : em);
                _Float16 h3 = (_Float16)(((R.a1 >> 24) & 255u) ? __expf(R.s1[3] - c) : em);
                unsigned* dst = (unsigned*)&sA[rb * 32 + kc];
                dst[0] = pk2(h0, h1); dst[1] = pk2(h2, h3);
            }
            {
                float c = stc[1], em = stem[1];
                _Float16 h0 = (_Float16)(((R.a2) & 255u) ? __expf(R.s2[0] - c) : em);
                _Float16 h1 = (_Float16)(((R.a2 >> 8) & 255u) ? __expf(R.s2[1] - c) : em);
                _Float16 h2 = (_Float16)(((R.a2 >> 16) & 255u) ? __expf(R.s2[2] - c) : em);
                _Float16 h3 = (_Float16)(((R.a2 >> 24) & 255u) ? __expf(R.s2[3] - c) : em);
                unsigned* dst = (unsigned*)&sA[(rb + 32) * 32 + kc];
                dst[0] = pk2(h0, h1); dst[1] = pk2(h2, h3);
            }
        }
    };
    auto storeB = [&]() {
        ((uint4*)sBh)[t] = rbh0; ((uint4*)sBh)[t + 256] = rbh1;
        ((uint4*)sBl)[t] = rbl0; ((uint4*)sBl)[t + 256] = rbl1;
    };
    auto compute = [&]() {
        half8 af[2], bfh[4], bfl[4];
        const int l4 = lane & 15, h = lane >> 4;
        const int cswz = TRANSA ? (h ^ ((l4 >> 2) & 3)) : h;
#pragma unroll
        for (int mi = 0; mi < 2; mi++)
            af[mi] = *(const half8*)&sA[(wm * 32 + mi * 16 + l4) * 32 + cswz * 8];
#pragma unroll
        for (int nj = 0; nj < 4; nj++) {
            int off = (wn * 64 + nj * 16 + l4) * 32 + h * 8;
            bfh[nj] = *(const half8*)&sBh[off];
            bfl[nj] = *(const half8*)&sBl[off];
        }
#pragma unroll
        for (int mi = 0; mi < 2; mi++)
#pragma unroll
            for (int nj = 0; nj < 4; nj++) {
                acc[mi][nj] = __builtin_amdgcn_mfma_f32_16x16x32_f16(af[mi], bfh[nj], acc[mi][nj], 0, 0, 0);
                acc[mi][nj] = __builtin_amdgcn_mfma_f32_16x16x32_f16(af[mi], bfl[nj], acc[mi][nj], 0, 0, 0);
            }
    };

    // prologue: A raw sets for kt=0 (A0) and kt=1 (A1); B regs for kt=0
    prefA_load(A0, 0);
    prefA_load(A1, 1);
    prefB(0);

    for (int kt = 0; kt < nk; kt += 2) {
        bar_entry();
        storeA(A0); storeB();                       // stage kt
        bar_commit();
        if (kt + 2 < nk) prefA_load(A0, kt + 2);    // raw A two phases ahead
        prefB(kt + 1);                              // B one phase ahead (nk even)
        compute();                                  // consume kt
        bar_entry();
        storeA(A1); storeB();                       // stage kt+1
        bar_commit();
        if (kt + 3 < nk) prefA_load(A1, kt + 3);
        if (kt + 2 < nk) prefB(kt + 2);
        compute();                                  // consume kt+1
    }

    const int rbase = (lane >> 4) * 4, cc = lane & 15;
#pragma unroll
    for (int mi = 0; mi < 2; mi++) {
#pragma unroll
        for (int nj = 0; nj < 4; nj++) {
            int gn = n0 + wn * 64 + nj * 16 + cc;
#pragma unroll
            for (int r = 0; r < 4; r++) {
                int gm = m0 + wm * 32 + mi * 16 + rbase + r;
                size_t off = ((size_t)bz * M + gm) * DD + gn;
                float v = acc[mi][nj][r] + addsrc[off];
                _Float16 h = (_Float16)v;
                Xhi[off] = h;
                Xlo[off] = (_Float16)(v - (float)h);
            }
        }
    }
}

// ---------------------------------------------------------------------------
// stats: ONE pass over S computes online-softmax (max, sum) partials for BOTH
// directions. Masked entries contribute x=0 (reference multiplies score*mask).
__global__ __launch_bounds__(256) void stats(const float* __restrict__ S_,
                                             const unsigned char* __restrict__ m1,
                                             const unsigned char* __restrict__ m2t,
                                             float2* __restrict__ d1p,
                                             float2* __restrict__ d2p) {
    int b = blockIdx.z, e0 = blockIdx.y * 64, n0 = blockIdx.x * 256;
    int t = threadIdx.x, lane = t & 63, w = t >> 6;
    size_t base = ((size_t)b * EE + e0) * NN + n0;

    f32x4 xs[16];
    unsigned int am[16], cm[16];
#pragma unroll
    for (int j = 0; j < 16; j++) {
        size_t off = base + (size_t)(w * 16 + j) * NN + lane * 4;
        float4 s = *(const float4*)(S_ + off);
        xs[j][0] = s.x; xs[j][1] = s.y; xs[j][2] = s.z; xs[j][3] = s.w;
        am[j] = *(const unsigned int*)(m1 + off);
        cm[j] = *(const unsigned int*)(m2t + off);
    }

    // ---- column stats (E-softmax, m1 mask)
    float cmx[4], csm[4];
#pragma unroll
    for (int i = 0; i < 4; i++) {
        float mx = ((am[0] >> (8 * i)) & 0xffu) ? xs[0][i] : 0.f;
#pragma unroll
        for (int j = 1; j < 16; j++) {
            float xe = ((am[j] >> (8 * i)) & 0xffu) ? xs[j][i] : 0.f;
            mx = fmaxf(mx, xe);
        }
        float sm = 0.f;
#pragma unroll
        for (int j = 0; j < 16; j++) {
            float xe = ((am[j] >> (8 * i)) & 0xffu) ? xs[j][i] : 0.f;
            sm += __expf(xe - mx);
        }
        cmx[i] = mx; csm[i] = sm;
    }
    __shared__ float rm[4][256], rs[4][256];
#pragma unroll
    for (int i = 0; i < 4; i++) { rm[w][lane * 4 + i] = cmx[i]; rs[w][lane * 4 + i] = csm[i]; }
    __syncthreads();
    {
        float M0 = rm[0][t], S0 = rs[0][t];
#pragma unroll
        for (int ww = 1; ww < 4; ww++) pmerge(M0, S0, rm[ww][t], rs[ww][t]);
        d1p[(size_t)blockIdx.y * (BB * NN) + (size_t)b * NN + n0 + t] = make_float2(M0, S0);
    }

    // ---- row stats (N-softmax, m2t mask)
#pragma unroll
    for (int j = 0; j < 16; j++) {
        float x0 = ((cm[j]) & 0xffu) ? xs[j][0] : 0.f;
        float x1 = ((cm[j] >> 8) & 0xffu) ? xs[j][1] : 0.f;
        float x2 = ((cm[j] >> 16) & 0xffu) ? xs[j][2] : 0.f;
        float x3 = ((cm[j] >> 24) & 0xffu) ? xs[j][3] : 0.f;
        float mx = fmaxf(fmaxf(x0, x1), fmaxf(x2, x3));
#pragma unroll
        for (int off = 1; off < 64; off <<= 1) mx = fmaxf(mx, __shfl_xor(mx, off, 64));
        float sm = __expf(x0 - mx) + __expf(x1 - mx) + __expf(x2 - mx) + __expf(x3 - mx);
#pragma unroll
        for (int off = 1; off < 64; off <<= 1) sm += __shfl_xor(sm, off, 64);
        if (lane == 0)
            d2p[(size_t)blockIdx.x * (BB * EE) + (size_t)b * EE + e0 + w * 16 + j] = make_float2(mx, sm);
    }
}

// merge partials -> (c = m + ln(sum), e^-c) for the fused-agg staging
__global__ void reduce_dens(const float2* __restrict__ d1p, const float2* __restrict__ d2p,
                            float2* __restrict__ d1, float2* __restrict__ d2) {
    int i = blockIdx.x * 256 + threadIdx.x;
    if (i < BB * NN) {
        float2 v = d1p[i];
        float m = v.x, s = v.y;
#pragma unroll
        for (int k = 1; k < 16; k++) {
            float2 u = d1p[(size_t)k * (BB * NN) + i];
            pmerge(m, s, u.x, u.y);
        }
        float c = m + __logf(s);
        d1[i] = make_float2(c, __expf(-c));
    } else {
        int j = i - BB * NN;
        if (j < BB * EE) {
            float2 v = d2p[j];
            float m = v.x, s = v.y;
#pragma unroll
            for (int k = 1; k < 8; k++) {
                float2 u = d2p[(size_t)k * (BB * EE) + j];
                pmerge(m, s, u.x, u.y);
            }
            float c = m + __logf(s);
            d2[j] = make_float2(c, __expf(-c));
        }
    }
}

// ---------------------------------------------------------------------------
extern "C" void kernel_launch(void* const* d_in, const int* in_sizes, int n_in,
                              void* d_out, int out_size, void* d_ws, size_t ws_size,
                              hipStream_t stream) {
    const float* evid   = (const float*)d_in[0];   // [B,E,D]
    const float* enti   = (const float*)d_in[1];   // [B,N,D]
    const float* ev2ent = (const float*)d_in[2];   // [B,E,N]
    const float* ent2ev = (const float*)d_in[3];   // [B,N,E]
    const float* w_w    = (const float*)d_in[4];   // [L,D,D]
    const float* w_b    = (const float*)d_in[5];   // [L,D]
    const float* wa_w   = (const float*)d_in[6];   // [L,D,D]
    const float* wa_b   = (const float*)d_in[7];   // [L,D]
    float* out_ent = (float*)d_out;                           // [B,N,D]
    float* out_ev  = out_ent + (size_t)BB * NN * DD;          // [B,E,D]

    char* p = (char*)d_ws;
    auto alloc = [&](size_t bytes) {
        char* r = p;
        p += (bytes + 255) & ~(size_t)255;
        return (void*)r;
    };
    const size_t nED = (size_t)BB * EE * DD, nND = (size_t)BB * NN * DD;
    const size_t nEN = (size_t)BB * EE * NN, nW = (size_t)LL * DD * DD;
    _Float16* Whi  = (_Float16*)alloc(nW * 2);
    _Float16* Wlo  = (_Float16*)alloc(nW * 2);
    _Float16* Wahi = (_Float16*)alloc(nW * 2);
    _Float16* Walo = (_Float16*)alloc(nW * 2);
    _Float16* evh  = (_Float16*)alloc(nED * 2);
    _Float16* evl  = (_Float16*)alloc(nED * 2);
    _Float16* enth = (_Float16*)alloc(nND * 2);
    _Float16* entl = (_Float16*)alloc(nND * 2);
    _Float16* evTh = (_Float16*)alloc(nED * 2);
    _Float16* evTl = (_Float16*)alloc(nED * 2);
    _Float16* entTh= (_Float16*)alloc(nND * 2);
    _Float16* entTl= (_Float16*)alloc(nND * 2);
    _Float16* peh  = (_Float16*)alloc(nED * 2);
    _Float16* pel  = (_Float16*)alloc(nED * 2);
    _Float16* pnh  = (_Float16*)alloc(nND * 2);
    _Float16* pnl  = (_Float16*)alloc(nND * 2);
    float*    S    = (float*)alloc(nEN * 4);
    unsigned char* m1  = (unsigned char*)alloc(nEN);
    unsigned char* m2t = (unsigned char*)alloc(nEN);
    float* evS  = (float*)alloc(nED * 4);
    float* entS = (float*)alloc(nND * 4);
    float2* d1p = (float2*)alloc((size_t)16 * BB * NN * 8);
    float2* d2p = (float2*)alloc((size_t)8 * BB * EE * 8);
    float2* d1  = (float2*)alloc((size_t)BB * NN * 8);
    float2* d2  = (float2*)alloc((size_t)BB * EE * 8);
    if ((size_t)(p - (char*)d_ws) > ws_size) return;  // workspace too small — bail
    _Float16* Xenth = pnh; _Float16* Xentl = pnl;  // alias: pn consumed before Xent written
    _Float16* Xevh  = peh; _Float16* Xevl  = pel;  // alias: pe consumed before Xev written

    // ---- setup ----
    split_cast<<<2048, 256, 0, stream>>>(wa_w, Wahi, Walo, nW);
    split_cast<<<2048, 256, 0, stream>>>(w_w, Whi, Wlo, nW);
    split_cast<<<2048, 256, 0, stream>>>(evid, evh, evl, nED);
    split_cast<<<2048, 256, 0, stream>>>(enti, enth, entl, nND);
    cast_u8<<<2048, 256, 0, stream>>>(ev2ent, m1, nEN);
    transpose_u8<<<dim3(EE / 64, NN / 64, BB), 256, 0, stream>>>(ent2ev, m2t, NN, EE);
    transpose_split_perm<<<dim3(DD / 64, EE / 64, BB), 256, 0, stream>>>(evid, evTh, evTl, EE, DD);
    hipMemcpyAsync(evS, evid, nED * 4, hipMemcpyDeviceToDevice, stream);
    hipMemcpyAsync(entS, enti, nND * 4, hipMemcpyDeviceToDevice, stream);

    for (int i = 0; i < LL; i++) {
        const _Float16* Wih  = Whi + (size_t)i * DD * DD;
        const _Float16* Wil  = Wlo + (size_t)i * DD * DD;
        const _Float16* Waih = Wahi + (size_t)i * DD * DD;
        const _Float16* Wail = Walo + (size_t)i * DD * DD;
        const float* bi  = w_b + i * DD;
        const float* bai = wa_b + i * DD;

        // 1. pe = ev @ Watt^T + bias  (split out)
        gemm_nt<true, true, true, false, false, false, true, false>
            <<<dim3(EE / 128, DD / 128, BB), 256, 0, stream>>>(
                evh, evl, Waih, Wail, bai, 1.f, nullptr, nullptr, peh, pel, EE, DD, DD);
        // 2. pn = ent @ Watt^T + bias
        gemm_nt<true, true, true, false, false, false, true, false>
            <<<dim3(NN / 128, DD / 128, BB), 256, 0, stream>>>(
                enth, entl, Waih, Wail, bai, 1.f, nullptr, nullptr, pnh, pnl, NN, DD, DD);
        // 3. S = pe @ pn^T  (f32)
        gemm_nt<true, true, false, false, false, true, false, true>
            <<<dim3(EE / 128, NN / 128, BB), 256, 0, stream>>>(
                peh, pel, pnh, pnl, nullptr, 0.f, nullptr, S, nullptr, nullptr, EE, NN, DD);
        // 4. exact online-softmax stats for both directions, one pass over S
        stats<<<dim3(NN / 256, EE / 64, BB), 256, 0, stream>>>(S, m1, m2t, d1p, d2p);
        reduce_dens<<<(BB * NN + BB * EE + 255) / 256, 256, 0, stream>>>(d1p, d2p, d1, d2);
        // 5. Xent = split(softmaxE(S*m1)^T @ evT^T + ent_old)   [fused norm+agg]
        fused_agg<true><<<dim3(NN / 64, 2, BB), 256, 0, stream>>>(
            S, m1, d1, evTh, evTl, entS, Xenth, Xentl, NN, EE);
        // 6. ent_new = relu(Xent @ W^T + 2b)  (f32 state/out + split)
        float* entDst = (i == LL - 1) ? out_ent : entS;
        gemm_nt<true, true, true, true, false, true, true, false>
            <<<dim3(NN / 128, DD / 128, BB), 256, 0, stream>>>(
                Xenth, Xentl, Wih, Wil, bi, 2.f, nullptr, entDst, enth, entl, NN, DD, DD);
        // 7. entT = transpose(ent_new) (split, linear) — feeds agg2 this layer
        transpose_split<<<dim3(DD / 64, NN / 64, BB), 256, 0, stream>>>(entDst, entTh, entTl, NN, DD);
        // 8. Xev = split(softmaxN(S*m2t) @ entT^T + ev_old)     [fused norm+agg]
        fused_agg<false><<<dim3(EE / 64, 2, BB), 256, 0, stream>>>(
            S, m2t, d2, entTh, entTl, evS, Xevh, Xevl, EE, NN);
        // 9. ev_new = relu(Xev @ W^T + 2b)
        float* evDst = (i == LL - 1) ? out_ev : evS;
        gemm_nt<true, true, true, true, false, true, true, false>
            <<<dim3(EE / 128, DD / 128, BB), 256, 0, stream>>>(
                Xevh, Xevl, Wih, Wil, bi, 2.f, nullptr, evDst, evh, evl, EE, DD, DD);
        // 10. evT (permuted) for next layer
        if (i < LL - 1)
            transpose_split_perm<<<dim3(DD / 64, EE / 64, BB), 256, 0, stream>>>(evS, evTh, evTl, EE, DD);
    }
}

// Round 12
// 1299.190 us; speedup vs baseline: 1.0518x; 1.0518x over previous
//
#include <hip/hip_runtime.h>

// Shapes (fixed by the problem)
#define BB 16
#define EE 1024
#define NN 2048
#define DD 256
#define LL 3

typedef _Float16 half8 __attribute__((ext_vector_type(8)));
typedef _Float16 half4 __attribute__((ext_vector_type(4)));
typedef _Float16 half2_t __attribute__((ext_vector_type(2)));
typedef float f32x4 __attribute__((ext_vector_type(4)));

// online-softmax pair merge: (m,s) <- (m,s) + (m2,s2)
__device__ __forceinline__ void pmerge(float& m, float& s, float m2, float s2) {
    float nm = fmaxf(m, m2);
    s = s * __expf(m - nm) + s2 * __expf(m2 - nm);
    m = nm;
}

__device__ __forceinline__ unsigned pk2(_Float16 a, _Float16 b) {
    union { _Float16 h[2]; unsigned u; } x;
    x.h[0] = a; x.h[1] = b;
    return x.u;
}

// ---------------------------------------------------------------------------
// f32 -> (hi, lo) f16 split cast: x = hi + lo, hi = f16(x), lo = f16(x - hi)
__global__ void split_cast(const float* __restrict__ in, _Float16* __restrict__ hi,
                           _Float16* __restrict__ lo, size_t n) {
    size_t stride = (size_t)gridDim.x * blockDim.x * 4;
    for (size_t i = ((size_t)blockIdx.x * blockDim.x + threadIdx.x) * 4; i < n; i += stride) {
        float4 v = *(const float4*)&in[i];
        half4 hh, ll;
        _Float16 h;
        h = (_Float16)v.x; hh[0] = h; ll[0] = (_Float16)(v.x - (float)h);
        h = (_Float16)v.y; hh[1] = h; ll[1] = (_Float16)(v.y - (float)h);
        h = (_Float16)v.z; hh[2] = h; ll[2] = (_Float16)(v.z - (float)h);
        h = (_Float16)v.w; hh[3] = h; ll[3] = (_Float16)(v.w - (float)h);
        *(half4*)&hi[i] = hh;
        *(half4*)&lo[i] = ll;
    }
}

// f32 (exact 0/1) -> u8
__global__ void cast_u8(const float* __restrict__ in, unsigned char* __restrict__ out, size_t n) {
    size_t stride = (size_t)gridDim.x * blockDim.x * 4;
    for (size_t i = ((size_t)blockIdx.x * blockDim.x + threadIdx.x) * 4; i < n; i += stride) {
        float4 v = *(const float4*)&in[i];
        unsigned int pack = (unsigned int)(unsigned char)v.x |
                            ((unsigned int)(unsigned char)v.y << 8) |
                            ((unsigned int)(unsigned char)v.z << 16) |
                            ((unsigned int)(unsigned char)v.w << 24);
        *(unsigned int*)&out[i] = pack;
    }
}

// ---------------------------------------------------------------------------
// per-batch transpose + split cast: in [R,C] f32 -> oh/ol [C,R] f16
__global__ void transpose_split(const float* __restrict__ in, _Float16* __restrict__ oh,
                                _Float16* __restrict__ olo, int R, int C) {
    int b = blockIdx.z;
    int c0 = blockIdx.x * 64, r0 = blockIdx.y * 64;
    const float* ib = in + (size_t)b * R * C;
    size_t ob = (size_t)b * R * C;
    __shared__ float tile[64][65];
    int t = threadIdx.x;
    int cl = t & 63, rb = t >> 6;
#pragma unroll
    for (int j = 0; j < 16; j++) {
        int rl = rb + j * 4;
        tile[rl][cl] = ib[(size_t)(r0 + rl) * C + c0 + cl];
    }
    __syncthreads();
    int oc = t >> 2, q = t & 3;
    half8 h0, h1, l0, l1;
#pragma unroll
    for (int i = 0; i < 8; i++) {
        float v = tile[q * 16 + i][oc];
        _Float16 h = (_Float16)v;
        h0[i] = h; l0[i] = (_Float16)(v - (float)h);
    }
#pragma unroll
    for (int i = 0; i < 8; i++) {
        float v = tile[q * 16 + 8 + i][oc];
        _Float16 h = (_Float16)v;
        h1[i] = h; l1[i] = (_Float16)(v - (float)h);
    }
    size_t o = ob + (size_t)(c0 + oc) * R + r0 + q * 16;
    *(half8*)&oh[o] = h0; *(half8*)&oh[o + 8] = h1;
    *(half8*)&olo[o] = l0; *(half8*)&olo[o + 8] = l1;
}

// transpose + split cast with e-pair PERMUTATION within each 32-block of R:
// out position (within 32-group) 2x holds e-local x, 2x+1 holds x+16.
// Matches fused_agg<true>'s A-LDS k-slot order so A and B share one k-perm.
__global__ void transpose_split_perm(const float* __restrict__ in, _Float16* __restrict__ oh,
                                     _Float16* __restrict__ olo, int R, int C) {
    int b = blockIdx.z;
    int c0 = blockIdx.x * 64, r0 = blockIdx.y * 64;
    const float* ib = in + (size_t)b * R * C;
    size_t ob = (size_t)b * R * C;
    __shared__ float tile[64][65];
    int t = threadIdx.x;
    int cl = t & 63, rb = t >> 6;
#pragma unroll
    for (int j = 0; j < 16; j++) {
        int rl = rb + j * 4;
        tile[rl][cl] = ib[(size_t)(r0 + rl) * C + c0 + cl];
    }
    __syncthreads();
    int oc = t >> 2, q = t & 3;
    int g = q >> 1, sub = q & 1;
#pragma unroll
    for (int j = 0; j < 8; j++) {
        int x = sub * 8 + j;
        float v1 = tile[g * 32 + x][oc];
        float v2 = tile[g * 32 + x + 16][oc];
        _Float16 a = (_Float16)v1, b2 = (_Float16)v2;
        _Float16 la = (_Float16)(v1 - (float)a), lb = (_Float16)(v2 - (float)b2);
        size_t o = ob + (size_t)(c0 + oc) * R + r0 + g * 32 + 2 * x;
        half2_t hp; hp[0] = a; hp[1] = b2;
        half2_t lp; lp[0] = la; lp[1] = lb;
        *(half2_t*)&oh[o] = hp;
        *(half2_t*)&olo[o] = lp;
    }
}

// per-batch transpose: in [R,C] f32 (exact 0/1) -> out [C,R] u8
__global__ void transpose_u8(const float* __restrict__ in, unsigned char* __restrict__ out,
                             int R, int C) {
    int b = blockIdx.z;
    int c0 = blockIdx.x * 64, r0 = blockIdx.y * 64;
    const float* ib = in + (size_t)b * R * C;
    unsigned char* ob = out + (size_t)b * R * C;
    __shared__ float tile[64][65];
    int t = threadIdx.x;
    int cl = t & 63, rb = t >> 6;
#pragma unroll
    for (int j = 0; j < 16; j++) {
        int rl = rb + j * 4;
        tile[rl][cl] = ib[(size_t)(r0 + rl) * C + c0 + cl];
    }
    __syncthreads();
    int oc = t >> 2, q = t & 3;
    union { unsigned char b[16]; uint4 v; } u;
#pragma unroll
    for (int i = 0; i < 16; i++) u.b[i] = (unsigned char)tile[q * 16 + i][oc];
    size_t o = (size_t)(c0 + oc) * R + r0 + q * 16;
    *(uint4*)&ob[o] = u.v;
}

// ---------------------------------------------------------------------------
// NT GEMM with split-f16 emulated-fp32 operands (3 passes: hh + hl + lh)
template <bool A_SPLIT, bool B_SPLIT, bool HAS_BIAS, bool RELU, bool HAS_ADD,
          bool WRITE_F32, bool WRITE_SPLIT, bool B_BATCHED>
__global__ __launch_bounds__(256) void gemm_nt(
    const _Float16* __restrict__ Ah, const _Float16* __restrict__ Al,
    const _Float16* __restrict__ Bh, const _Float16* __restrict__ Bl,
    const float* __restrict__ bias, float bscale,
    const float* __restrict__ addsrc,
    float* __restrict__ Cf, _Float16* __restrict__ Chi, _Float16* __restrict__ Clo,
    int M, int Nn, int K) {
    const int bz = blockIdx.z;
    const int m0 = blockIdx.x * 128, n0 = blockIdx.y * 128;
    const int t = threadIdx.x, lane = t & 63, wid = t >> 6;
    const int wm = wid >> 1, wn = wid & 1;
    const size_t offA = (size_t)bz * M * K;
    const size_t offB = B_BATCHED ? (size_t)bz * Nn * K : (size_t)0;
    const _Float16* Abh = Ah + offA;
    const _Float16* Abl = A_SPLIT ? (Al + offA) : nullptr;
    const _Float16* Bbh = Bh + offB;
    const _Float16* Bbl = B_SPLIT ? (Bl + offB) : nullptr;

    __shared__ _Float16 sAh[128 * 32];
    __shared__ _Float16 sBh[128 * 32];
    __shared__ _Float16 sAl[A_SPLIT ? 128 * 32 : 1];
    __shared__ _Float16 sBl[B_SPLIT ? 128 * 32 : 1];

    f32x4 acc[4][4] = {};
    const int nk = K >> 5;

    auto gA = [&](const _Float16* base, int kt, int q) {
        return *(const uint4*)(base + (size_t)(m0 + (q >> 2)) * K + (kt << 5) + ((q & 3) << 3));
    };
    auto gB = [&](const _Float16* base, int kt, int q) {
        return *(const uint4*)(base + (size_t)(n0 + (q >> 2)) * K + (kt << 5) + ((q & 3) << 3));
    };

    uint4 rah0 = gA(Abh, 0, t), rah1 = gA(Abh, 0, t + 256);
    uint4 rbh0 = gB(Bbh, 0, t), rbh1 = gB(Bbh, 0, t + 256);
    uint4 ral0 = {}, ral1 = {}, rbl0 = {}, rbl1 = {};
    if (A_SPLIT) { ral0 = gA(Abl, 0, t); ral1 = gA(Abl, 0, t + 256); }
    if (B_SPLIT) { rbl0 = gB(Bbl, 0, t); rbl1 = gB(Bbl, 0, t + 256); }

    for (int kt = 0; kt < nk; ++kt) {
        __syncthreads();
        ((uint4*)sAh)[t] = rah0; ((uint4*)sAh)[t + 256] = rah1;
        ((uint4*)sBh)[t] = rbh0; ((uint4*)sBh)[t + 256] = rbh1;
        if (A_SPLIT) { ((uint4*)sAl)[t] = ral0; ((uint4*)sAl)[t + 256] = ral1; }
        if (B_SPLIT) { ((uint4*)sBl)[t] = rbl0; ((uint4*)sBl)[t + 256] = rbl1; }
        __syncthreads();
        if (kt + 1 < nk) {
            rah0 = gA(Abh, kt + 1, t); rah1 = gA(Abh, kt + 1, t + 256);
            rbh0 = gB(Bbh, kt + 1, t); rbh1 = gB(Bbh, kt + 1, t + 256);
            if (A_SPLIT) { ral0 = gA(Abl, kt + 1, t); ral1 = gA(Abl, kt + 1, t + 256); }
            if (B_SPLIT) { rbl0 = gB(Bbl, kt + 1, t); rbl1 = gB(Bbl, kt + 1, t + 256); }
        }
        half8 afh[4], bfh[4], afl[4], bfl[4];
#pragma unroll
        for (int mi = 0; mi < 4; mi++) {
            int off = (wm * 64 + mi * 16 + (lane & 15)) * 32 + ((lane >> 4) << 3);
            afh[mi] = *(const half8*)&sAh[off];
            if (A_SPLIT) afl[mi] = *(const half8*)&sAl[off];
        }
#pragma unroll
        for (int nj = 0; nj < 4; nj++) {
            int off = (wn * 64 + nj * 16 + (lane & 15)) * 32 + ((lane >> 4) << 3);
            bfh[nj] = *(const half8*)&sBh[off];
            if (B_SPLIT) bfl[nj] = *(const half8*)&sBl[off];
        }
#pragma unroll
        for (int mi = 0; mi < 4; mi++)
#pragma unroll
            for (int nj = 0; nj < 4; nj++) {
                acc[mi][nj] = __builtin_amdgcn_mfma_f32_16x16x32_f16(afh[mi], bfh[nj], acc[mi][nj], 0, 0, 0);
                if (B_SPLIT)
                    acc[mi][nj] = __builtin_amdgcn_mfma_f32_16x16x32_f16(afh[mi], bfl[nj], acc[mi][nj], 0, 0, 0);
                if (A_SPLIT)
                    acc[mi][nj] = __builtin_amdgcn_mfma_f32_16x16x32_f16(afl[mi], bfh[nj], acc[mi][nj], 0, 0, 0);
            }
    }

    const int rbase = (lane >> 4) * 4, cc = lane & 15;
#pragma unroll
    for (int mi = 0; mi < 4; mi++) {
#pragma unroll
        for (int nj = 0; nj < 4; nj++) {
            int gn = n0 + wn * 64 + nj * 16 + cc;
            float bv = HAS_BIAS ? bias[gn] * bscale : 0.f;
#pragma unroll
            for (int r = 0; r < 4; r++) {
                int gm = m0 + wm * 64 + mi * 16 + rbase + r;
                float v = acc[mi][nj][r];
                if (HAS_BIAS) v += bv;
                size_t off = ((size_t)bz * M + gm) * Nn + gn;
                if (HAS_ADD) v += addsrc[off];
                if (RELU) v = fmaxf(v, 0.f);
                if (WRITE_F32) Cf[off] = v;
                if (WRITE_SPLIT) {
                    _Float16 h = (_Float16)v;
                    Chi[off] = h;
                    Clo[off] = (_Float16)(v - (float)h);
                }
            }
        }
    }
}

// ---------------------------------------------------------------------------
// FUSED normalize + aggregation GEMM:
//   X[b][m][d] = (softmax-normalized P)[m][k] @ B[d][k]^T + addsrc, split-f16 out
// A-tile is computed on the fly from S + mask + per-m stats (c = max+ln(sum)):
//   P[m][k] = msk ? exp(s - c[m]) : exp(-c[m])
// TRANSA=true  (agg1): transposed staging, e-pair k-perm + XOR swizzle;
//   B (evT) pre-permuted to the same k-order (transpose_split_perm).
// TRANSA=false (agg2): direct row-major staging.
// 64x128 tile, 256 threads, 2x2 waves, wave tile 32x64 (champion geometry,
// R9 = 1359 µs). R12 change: BK 32 -> 64. The aggs ran 16 MFMAs per
// 2-barrier k-step vs the S-GEMM's 48 (85 µs at same output shape) — the
// per-step stage+barrier fixed cost dominated (m233 regime). BK=64 halves
// the step count and doubles MFMA/step to 32 with IDENTICAL global traffic
// and block geometry. LDS is two side-by-side 32-col buffers (per-buffer
// layout byte-identical to champion -> same bank behavior). 40 KB LDS,
// still 2-4 blocks/CU. agg1 nk=16, agg2 nk=32.
template <bool TRANSA>
__global__ __launch_bounds__(256) void fused_agg(
    const float* __restrict__ S_, const unsigned char* __restrict__ Mk,
    const float2* __restrict__ st, const _Float16* __restrict__ Bh,
    const _Float16* __restrict__ Bl, const float* __restrict__ addsrc,
    _Float16* __restrict__ Xhi, _Float16* __restrict__ Xlo,
    int M, int K) {
    const int bz = blockIdx.z;
    const int m0 = blockIdx.x * 64, n0 = blockIdx.y * 128;
    const int t = threadIdx.x, lane = t & 63, wid = t >> 6;
    const int wm = wid >> 1, wn = wid & 1;   // 2x2 waves; wave tile 32(m) x 64(n)
    const float* Sb = S_ + (size_t)bz * EE * NN;
    const unsigned char* Mb = Mk + (size_t)bz * EE * NN;
    const float2* stb = st + (size_t)bz * M;
    const _Float16* Bbh = Bh + (size_t)bz * DD * K;
    const _Float16* Bbl = Bl + (size_t)bz * DD * K;

    __shared__ _Float16 sA[2 * 64 * 32];     //  8 KB: two 32-col A buffers
    __shared__ _Float16 sBh[2 * 128 * 32];   // 16 KB
    __shared__ _Float16 sBl[2 * 128 * 32];   // 16 KB

    f32x4 acc[2][4] = {};
    const int nk = K >> 6;   // BK=64: 16 (agg1) or 32 (agg2)

    // hoisted per-thread softmax stats (c, e^-c)
    float stc[4], stem[4];
    if (TRANSA) {
        int ncol = (t & 15) * 4;
#pragma unroll
        for (int i = 0; i < 4; i++) {
            float2 v = stb[m0 + ncol + i];
            stc[i] = v.x; stem[i] = v.y;
        }
    } else {
#pragma unroll
        for (int p = 0; p < 2; p++) {
            float2 v = stb[m0 + (t >> 3) + p * 32];
            stc[p] = v.x; stem[p] = v.y;
        }
    }

    unsigned apack[2][4];
    uint4 rbh0[2], rbh1[2], rbl0[2], rbl1[2];

    // c = global 32-wide k-chunk index; h2 = which half-buffer (0/1)
    auto prefA = [&](int c, int h2) {
        if (TRANSA) {
            int r = t >> 4, ncol = (t & 15) * 4, e0 = c * 32;
            size_t rowoff = (size_t)(e0 + r) * NN + m0 + ncol;
            f32x4 s1 = *(const f32x4*)(Sb + rowoff);
            f32x4 s2 = *(const f32x4*)(Sb + rowoff + (size_t)16 * NN);
            unsigned a1 = *(const unsigned*)(Mb + rowoff);
            unsigned a2 = *(const unsigned*)(Mb + rowoff + (size_t)16 * NN);
#pragma unroll
            for (int i = 0; i < 4; i++) {
                float cc_ = stc[i], em = stem[i];
                float x1 = ((a1 >> (8 * i)) & 255u) ? __expf(s1[i] - cc_) : em;
                float x2 = ((a2 >> (8 * i)) & 255u) ? __expf(s2[i] - cc_) : em;
                apack[h2][i] = pk2((_Float16)x1, (_Float16)x2);
            }
        } else {
            int kc = (t & 7) * 4, rb = t >> 3;
#pragma unroll
            for (int p = 0; p < 2; p++) {
                size_t rowoff = (size_t)(m0 + rb + p * 32) * NN + c * 32 + kc;
                f32x4 s = *(const f32x4*)(Sb + rowoff);
                unsigned a = *(const unsigned*)(Mb + rowoff);
                float cc_ = stc[p], em = stem[p];
                _Float16 h0 = (_Float16)(((a) & 255u) ? __expf(s[0] - cc_) : em);
                _Float16 h1 = (_Float16)(((a >> 8) & 255u) ? __expf(s[1] - cc_) : em);
                _Float16 h2v = (_Float16)(((a >> 16) & 255u) ? __expf(s[2] - cc_) : em);
                _Float16 h3 = (_Float16)(((a >> 24) & 255u) ? __expf(s[3] - cc_) : em);
                apack[h2][2 * p] = pk2(h0, h1);
                apack[h2][2 * p + 1] = pk2(h2v, h3);
            }
        }
    };
    auto prefB = [&](int c, int h2) {
        auto g = [&](const _Float16* base, int q) {
            return *(const uint4*)(base + (size_t)(n0 + (q >> 2)) * K + c * 32 + (q & 3) * 8);
        };
        rbh0[h2] = g(Bbh, t); rbh1[h2] = g(Bbh, t + 256);
        rbl0[h2] = g(Bbl, t); rbl1[h2] = g(Bbl, t + 256);
    };
    auto storeAB = [&]() {
#pragma unroll
        for (int h2 = 0; h2 < 2; h2++) {
            unsigned* sAw = (unsigned*)(sA + h2 * (64 * 32));
            if (TRANSA) {
                int r = t >> 4, ncol = (t & 15) * 4;
#pragma unroll
                for (int i = 0; i < 4; i++) {
                    int n = ncol + i;
                    int cp = (r >> 2) ^ ((n >> 2) & 3);
                    sAw[n * 16 + cp * 4 + (r & 3)] = apack[h2][i];
                }
            } else {
                int kc = (t & 7) * 4, rb = t >> 3;
#pragma unroll
                for (int p = 0; p < 2; p++) {
                    unsigned* dst = (unsigned*)(sA + h2 * (64 * 32) + (rb + p * 32) * 32 + kc);
                    dst[0] = apack[h2][2 * p]; dst[1] = apack[h2][2 * p + 1];
                }
            }
            ((uint4*)(sBh + h2 * (128 * 32)))[t] = rbh0[h2];
            ((uint4*)(sBh + h2 * (128 * 32)))[t + 256] = rbh1[h2];
            ((uint4*)(sBl + h2 * (128 * 32)))[t] = rbl0[h2];
            ((uint4*)(sBl + h2 * (128 * 32)))[t + 256] = rbl1[h2];
        }
    };

    prefA(0, 0); prefA(1, 1);
    prefB(0, 0); prefB(1, 1);

    const int l4 = lane & 15, hh = lane >> 4;
    const int cswz = TRANSA ? (hh ^ ((l4 >> 2) & 3)) : hh;

    for (int kt = 0; kt < nk; ++kt) {
        __syncthreads();
        storeAB();
        __syncthreads();
        if (kt + 1 < nk) {
            prefA(2 * kt + 2, 0); prefA(2 * kt + 3, 1);
            prefB(2 * kt + 2, 0); prefB(2 * kt + 3, 1);
        }
#pragma unroll
        for (int ks = 0; ks < 2; ks++) {
            half8 af[2], bfh[4], bfl[4];
#pragma unroll
            for (int mi = 0; mi < 2; mi++)
                af[mi] = *(const half8*)&sA[ks * (64 * 32) + (wm * 32 + mi * 16 + l4) * 32 + cswz * 8];
#pragma unroll
            for (int nj = 0; nj < 4; nj++) {
                int off = ks * (128 * 32) + (wn * 64 + nj * 16 + l4) * 32 + hh * 8;
                bfh[nj] = *(const half8*)&sBh[off];
                bfl[nj] = *(const half8*)&sBl[off];
            }
#pragma unroll
            for (int mi = 0; mi < 2; mi++)
#pragma unroll
                for (int nj = 0; nj < 4; nj++) {
                    acc[mi][nj] = __builtin_amdgcn_mfma_f32_16x16x32_f16(af[mi], bfh[nj], acc[mi][nj], 0, 0, 0);
                    acc[mi][nj] = __builtin_amdgcn_mfma_f32_16x16x32_f16(af[mi], bfl[nj], acc[mi][nj], 0, 0, 0);
                }
        }
    }

    const int rbase = (lane >> 4) * 4, cc = lane & 15;
#pragma unroll
    for (int mi = 0; mi < 2; mi++) {
#pragma unroll
        for (int nj = 0; nj < 4; nj++) {
            int gn = n0 + wn * 64 + nj * 16 + cc;
#pragma unroll
            for (int r = 0; r < 4; r++) {
                int gm = m0 + wm * 32 + mi * 16 + rbase + r;
                size_t off = ((size_t)bz * M + gm) * DD + gn;
                float v = acc[mi][nj][r] + addsrc[off];
                _Float16 h = (_Float16)v;
                Xhi[off] = h;
                Xlo[off] = (_Float16)(v - (float)h);
            }
        }
    }
}

// ---------------------------------------------------------------------------
// stats: ONE pass over S computes online-softmax (max, sum) partials for BOTH
// directions. Masked entries contribute x=0 (reference multiplies score*mask).
__global__ __launch_bounds__(256) void stats(const float* __restrict__ S_,
                                             const unsigned char* __restrict__ m1,
                                             const unsigned char* __restrict__ m2t,
                                             float2* __restrict__ d1p,
                                             float2* __restrict__ d2p) {
    int b = blockIdx.z, e0 = blockIdx.y * 64, n0 = blockIdx.x * 256;
    int t = threadIdx.x, lane = t & 63, w = t >> 6;
    size_t base = ((size_t)b * EE + e0) * NN + n0;

    f32x4 xs[16];
    unsigned int am[16], cm[16];
#pragma unroll
    for (int j = 0; j < 16; j++) {
        size_t off = base + (size_t)(w * 16 + j) * NN + lane * 4;
        float4 s = *(const float4*)(S_ + off);
        xs[j][0] = s.x; xs[j][1] = s.y; xs[j][2] = s.z; xs[j][3] = s.w;
        am[j] = *(const unsigned int*)(m1 + off);
        cm[j] = *(const unsigned int*)(m2t + off);
    }

    // ---- column stats (E-softmax, m1 mask)
    float cmx[4], csm[4];
#pragma unroll
    for (int i = 0; i < 4; i++) {
        float mx = ((am[0] >> (8 * i)) & 0xffu) ? xs[0][i] : 0.f;
#pragma unroll
        for (int j = 1; j < 16; j++) {
            float xe = ((am[j] >> (8 * i)) & 0xffu) ? xs[j][i] : 0.f;
            mx = fmaxf(mx, xe);
        }
        float sm = 0.f;
#pragma unroll
        for (int j = 0; j < 16; j++) {
            float xe = ((am[j] >> (8 * i)) & 0xffu) ? xs[j][i] : 0.f;
            sm += __expf(xe - mx);
        }
        cmx[i] = mx; csm[i] = sm;
    }
    __shared__ float rm[4][256], rs[4][256];
#pragma unroll
    for (int i = 0; i < 4; i++) { rm[w][lane * 4 + i] = cmx[i]; rs[w][lane * 4 + i] = csm[i]; }
    __syncthreads();
    {
        float M0 = rm[0][t], S0 = rs[0][t];
#pragma unroll
        for (int ww = 1; ww < 4; ww++) pmerge(M0, S0, rm[ww][t], rs[ww][t]);
        d1p[(size_t)blockIdx.y * (BB * NN) + (size_t)b * NN + n0 + t] = make_float2(M0, S0);
    }

    // ---- row stats (N-softmax, m2t mask)
#pragma unroll
    for (int j = 0; j < 16; j++) {
        float x0 = ((cm[j]) & 0xffu) ? xs[j][0] : 0.f;
        float x1 = ((cm[j] >> 8) & 0xffu) ? xs[j][1] : 0.f;
        float x2 = ((cm[j] >> 16) & 0xffu) ? xs[j][2] : 0.f;
        float x3 = ((cm[j] >> 24) & 0xffu) ? xs[j][3] : 0.f;
        float mx = fmaxf(fmaxf(x0, x1), fmaxf(x2, x3));
#pragma unroll
        for (int off = 1; off < 64; off <<= 1) mx = fmaxf(mx, __shfl_xor(mx, off, 64));
        float sm = __expf(x0 - mx) + __expf(x1 - mx) + __expf(x2 - mx) + __expf(x3 - mx);
#pragma unroll
        for (int off = 1; off < 64; off <<= 1) sm += __shfl_xor(sm, off, 64);
        if (lane == 0)
            d2p[(size_t)blockIdx.x * (BB * EE) + (size_t)b * EE + e0 + w * 16 + j] = make_float2(mx, sm);
    }
}

// merge partials -> (c = m + ln(sum), e^-c) for the fused-agg staging
__global__ void reduce_dens(const float2* __restrict__ d1p, const float2* __restrict__ d2p,
                            float2* __restrict__ d1, float2* __restrict__ d2) {
    int i = blockIdx.x * 256 + threadIdx.x;
    if (i < BB * NN) {
        float2 v = d1p[i];
        float m = v.x, s = v.y;
#pragma unroll
        for (int k = 1; k < 16; k++) {
            float2 u = d1p[(size_t)k * (BB * NN) + i];
            pmerge(m, s, u.x, u.y);
        }
        float c = m + __logf(s);
        d1[i] = make_float2(c, __expf(-c));
    } else {
        int j = i - BB * NN;
        if (j < BB * EE) {
            float2 v = d2p[j];
            float m = v.x, s = v.y;
#pragma unroll
            for (int k = 1; k < 8; k++) {
                float2 u = d2p[(size_t)k * (BB * EE) + j];
                pmerge(m, s, u.x, u.y);
            }
            float c = m + __logf(s);
            d2[j] = make_float2(c, __expf(-c));
        }
    }
}

// ---------------------------------------------------------------------------
extern "C" void kernel_launch(void* const* d_in, const int* in_sizes, int n_in,
                              void* d_out, int out_size, void* d_ws, size_t ws_size,
                              hipStream_t stream) {
    const float* evid   = (const float*)d_in[0];   // [B,E,D]
    const float* enti   = (const float*)d_in[1];   // [B,N,D]
    const float* ev2ent = (const float*)d_in[2];   // [B,E,N]
    const float* ent2ev = (const float*)d_in[3];   // [B,N,E]
    const float* w_w    = (const float*)d_in[4];   // [L,D,D]
    const float* w_b    = (const float*)d_in[5];   // [L,D]
    const float* wa_w   = (const float*)d_in[6];   // [L,D,D]
    const float* wa_b   = (const float*)d_in[7];   // [L,D]
    float* out_ent = (float*)d_out;                           // [B,N,D]
    float* out_ev  = out_ent + (size_t)BB * NN * DD;          // [B,E,D]

    char* p = (char*)d_ws;
    auto alloc = [&](size_t bytes) {
        char* r = p;
        p += (bytes + 255) & ~(size_t)255;
        return (void*)r;
    };
    const size_t nED = (size_t)BB * EE * DD, nND = (size_t)BB * NN * DD;
    const size_t nEN = (size_t)BB * EE * NN, nW = (size_t)LL * DD * DD;
    _Float16* Whi  = (_Float16*)alloc(nW * 2);
    _Float16* Wlo  = (_Float16*)alloc(nW * 2);
    _Float16* Wahi = (_Float16*)alloc(nW * 2);
    _Float16* Walo = (_Float16*)alloc(nW * 2);
    _Float16* evh  = (_Float16*)alloc(nED * 2);
    _Float16* evl  = (_Float16*)alloc(nED * 2);
    _Float16* enth = (_Float16*)alloc(nND * 2);
    _Float16* entl = (_Float16*)alloc(nND * 2);
    _Float16* evTh = (_Float16*)alloc(nED * 2);
    _Float16* evTl = (_Float16*)alloc(nED * 2);
    _Float16* entTh= (_Float16*)alloc(nND * 2);
    _Float16* entTl= (_Float16*)alloc(nND * 2);
    _Float16* peh  = (_Float16*)alloc(nED * 2);
    _Float16* pel  = (_Float16*)alloc(nED * 2);
    _Float16* pnh  = (_Float16*)alloc(nND * 2);
    _Float16* pnl  = (_Float16*)alloc(nND * 2);
    float*    S    = (float*)alloc(nEN * 4);
    unsigned char* m1  = (unsigned char*)alloc(nEN);
    unsigned char* m2t = (unsigned char*)alloc(nEN);
    float* evS  = (float*)alloc(nED * 4);
    float* entS = (float*)alloc(nND * 4);
    float2* d1p = (float2*)alloc((size_t)16 * BB * NN * 8);
    float2* d2p = (float2*)alloc((size_t)8 * BB * EE * 8);
    float2* d1  = (float2*)alloc((size_t)BB * NN * 8);
    float2* d2  = (float2*)alloc((size_t)BB * EE * 8);
    if ((size_t)(p - (char*)d_ws) > ws_size) return;  // workspace too small — bail
    _Float16* Xenth = pnh; _Float16* Xentl = pnl;  // alias: pn consumed before Xent written
    _Float16* Xevh  = peh; _Float16* Xevl  = pel;  // alias: pe consumed before Xev written

    // ---- setup ----
    split_cast<<<2048, 256, 0, stream>>>(wa_w, Wahi, Walo, nW);
    split_cast<<<2048, 256, 0, stream>>>(w_w, Whi, Wlo, nW);
    split_cast<<<2048, 256, 0, stream>>>(evid, evh, evl, nED);
    split_cast<<<2048, 256, 0, stream>>>(enti, enth, entl, nND);
    cast_u8<<<2048, 256, 0, stream>>>(ev2ent, m1, nEN);
    transpose_u8<<<dim3(EE / 64, NN / 64, BB), 256, 0, stream>>>(ent2ev, m2t, NN, EE);
    transpose_split_perm<<<dim3(DD / 64, EE / 64, BB), 256, 0, stream>>>(evid, evTh, evTl, EE, DD);
    hipMemcpyAsync(evS, evid, nED * 4, hipMemcpyDeviceToDevice, stream);
    hipMemcpyAsync(entS, enti, nND * 4, hipMemcpyDeviceToDevice, stream);

    for (int i = 0; i < LL; i++) {
        const _Float16* Wih  = Whi + (size_t)i * DD * DD;
        const _Float16* Wil  = Wlo + (size_t)i * DD * DD;
        const _Float16* Waih = Wahi + (size_t)i * DD * DD;
        const _Float16* Wail = Walo + (size_t)i * DD * DD;
        const float* bi  = w_b + i * DD;
        const float* bai = wa_b + i * DD;

        // 1. pe = ev @ Watt^T + bias  (split out)
        gemm_nt<true, true, true, false, false, false, true, false>
            <<<dim3(EE / 128, DD / 128, BB), 256, 0, stream>>>(
                evh, evl, Waih, Wail, bai, 1.f, nullptr, nullptr, peh, pel, EE, DD, DD);
        // 2. pn = ent @ Watt^T + bias
        gemm_nt<true, true, true, false, false, false, true, false>
            <<<dim3(NN / 128, DD / 128, BB), 256, 0, stream>>>(
                enth, entl, Waih, Wail, bai, 1.f, nullptr, nullptr, pnh, pnl, NN, DD, DD);
        // 3. S = pe @ pn^T  (f32)
        gemm_nt<true, true, false, false, false, true, false, true>
            <<<dim3(EE / 128, NN / 128, BB), 256, 0, stream>>>(
                peh, pel, pnh, pnl, nullptr, 0.f, nullptr, S, nullptr, nullptr, EE, NN, DD);
        // 4. exact online-softmax stats for both directions, one pass over S
        stats<<<dim3(NN / 256, EE / 64, BB), 256, 0, stream>>>(S, m1, m2t, d1p, d2p);
        reduce_dens<<<(BB * NN + BB * EE + 255) / 256, 256, 0, stream>>>(d1p, d2p, d1, d2);
        // 5. Xent = split(softmaxE(S*m1)^T @ evT^T + ent_old)   [fused norm+agg]
        fused_agg<true><<<dim3(NN / 64, 2, BB), 256, 0, stream>>>(
            S, m1, d1, evTh, evTl, entS, Xenth, Xentl, NN, EE);
        // 6. ent_new = relu(Xent @ W^T + 2b)  (f32 state/out + split)
        float* entDst = (i == LL - 1) ? out_ent : entS;
        gemm_nt<true, true, true, true, false, true, true, false>
            <<<dim3(NN / 128, DD / 128, BB), 256, 0, stream>>>(
                Xenth, Xentl, Wih, Wil, bi, 2.f, nullptr, entDst, enth, entl, NN, DD, DD);
        // 7. entT = transpose(ent_new) (split, linear) — feeds agg2 this layer
        transpose_split<<<dim3(DD / 64, NN / 64, BB), 256, 0, stream>>>(entDst, entTh, entTl, NN, DD);
        // 8. Xev = split(softmaxN(S*m2t) @ entT^T + ev_old)     [fused norm+agg]
        fused_agg<false><<<dim3(EE / 64, 2, BB), 256, 0, stream>>>(
            S, m2t, d2, entTh, entTl, evS, Xevh, Xevl, EE, NN);
        // 9. ev_new = relu(Xev @ W^T + 2b)
        float* evDst = (i == LL - 1) ? out_ev : evS;
        gemm_nt<true, true, true, true, false, true, true, false>
            <<<dim3(EE / 128, DD / 128, BB), 256, 0, stream>>>(
                Xevh, Xevl, Wih, Wil, bi, 2.f, nullptr, evDst, evh, evl, EE, DD, DD);
        // 10. evT (permuted) for next layer
        if (i < LL - 1)
            transpose_split_perm<<<dim3(DD / 64, EE / 64, BB), 256, 0, stream>>>(evS, evTh, evTl, EE, DD);
    }
}

// Round 13
// 1295.181 us; speedup vs baseline: 1.0551x; 1.0031x over previous
//
#include <hip/hip_runtime.h>

// Shapes (fixed by the problem)
#define BB 16
#define EE 1024
#define NN 2048
#define DD 256
#define LL 3

typedef _Float16 half8 __attribute__((ext_vector_type(8)));
typedef _Float16 half4 __attribute__((ext_vector_type(4)));
typedef _Float16 half2_t __attribute__((ext_vector_type(2)));
typedef float f32x4 __attribute__((ext_vector_type(4)));

// online-softmax pair merge: (m,s) <- (m,s) + (m2,s2)
__device__ __forceinline__ void pmerge(float& m, float& s, float m2, float s2) {
    float nm = fmaxf(m, m2);
    s = s * __expf(m - nm) + s2 * __expf(m2 - nm);
    m = nm;
}

__device__ __forceinline__ unsigned pk2(_Float16 a, _Float16 b) {
    union { _Float16 h[2]; unsigned u; } x;
    x.h[0] = a; x.h[1] = b;
    return x.u;
}

// ---------------------------------------------------------------------------
// f32 -> (hi, lo) f16 split cast: x = hi + lo, hi = f16(x), lo = f16(x - hi)
__global__ void split_cast(const float* __restrict__ in, _Float16* __restrict__ hi,
                           _Float16* __restrict__ lo, size_t n) {
    size_t stride = (size_t)gridDim.x * blockDim.x * 4;
    for (size_t i = ((size_t)blockIdx.x * blockDim.x + threadIdx.x) * 4; i < n; i += stride) {
        float4 v = *(const float4*)&in[i];
        half4 hh, ll;
        _Float16 h;
        h = (_Float16)v.x; hh[0] = h; ll[0] = (_Float16)(v.x - (float)h);
        h = (_Float16)v.y; hh[1] = h; ll[1] = (_Float16)(v.y - (float)h);
        h = (_Float16)v.z; hh[2] = h; ll[2] = (_Float16)(v.z - (float)h);
        h = (_Float16)v.w; hh[3] = h; ll[3] = (_Float16)(v.w - (float)h);
        *(half4*)&hi[i] = hh;
        *(half4*)&lo[i] = ll;
    }
}

// f32 (exact 0/1) -> u8
__global__ void cast_u8(const float* __restrict__ in, unsigned char* __restrict__ out, size_t n) {
    size_t stride = (size_t)gridDim.x * blockDim.x * 4;
    for (size_t i = ((size_t)blockIdx.x * blockDim.x + threadIdx.x) * 4; i < n; i += stride) {
        float4 v = *(const float4*)&in[i];
        unsigned int pack = (unsigned int)(unsigned char)v.x |
                            ((unsigned int)(unsigned char)v.y << 8) |
                            ((unsigned int)(unsigned char)v.z << 16) |
                            ((unsigned int)(unsigned char)v.w << 24);
        *(unsigned int*)&out[i] = pack;
    }
}

// ---------------------------------------------------------------------------
// per-batch transpose + split cast: in [R,C] f32 -> oh/ol [C,R] f16
__global__ void transpose_split(const float* __restrict__ in, _Float16* __restrict__ oh,
                                _Float16* __restrict__ olo, int R, int C) {
    int b = blockIdx.z;
    int c0 = blockIdx.x * 64, r0 = blockIdx.y * 64;
    const float* ib = in + (size_t)b * R * C;
    size_t ob = (size_t)b * R * C;
    __shared__ float tile[64][65];
    int t = threadIdx.x;
    int cl = t & 63, rb = t >> 6;
#pragma unroll
    for (int j = 0; j < 16; j++) {
        int rl = rb + j * 4;
        tile[rl][cl] = ib[(size_t)(r0 + rl) * C + c0 + cl];
    }
    __syncthreads();
    int oc = t >> 2, q = t & 3;
    half8 h0, h1, l0, l1;
#pragma unroll
    for (int i = 0; i < 8; i++) {
        float v = tile[q * 16 + i][oc];
        _Float16 h = (_Float16)v;
        h0[i] = h; l0[i] = (_Float16)(v - (float)h);
    }
#pragma unroll
    for (int i = 0; i < 8; i++) {
        float v = tile[q * 16 + 8 + i][oc];
        _Float16 h = (_Float16)v;
        h1[i] = h; l1[i] = (_Float16)(v - (float)h);
    }
    size_t o = ob + (size_t)(c0 + oc) * R + r0 + q * 16;
    *(half8*)&oh[o] = h0; *(half8*)&oh[o + 8] = h1;
    *(half8*)&olo[o] = l0; *(half8*)&olo[o + 8] = l1;
}

// transpose + split cast with e-pair PERMUTATION within each 32-block of R:
// out position (within 32-group) 2x holds e-local x, 2x+1 holds x+16.
// Matches fused_agg<true>'s A-LDS k-slot order so A and B share one k-perm.
__global__ void transpose_split_perm(const float* __restrict__ in, _Float16* __restrict__ oh,
                                     _Float16* __restrict__ olo, int R, int C) {
    int b = blockIdx.z;
    int c0 = blockIdx.x * 64, r0 = blockIdx.y * 64;
    const float* ib = in + (size_t)b * R * C;
    size_t ob = (size_t)b * R * C;
    __shared__ float tile[64][65];
    int t = threadIdx.x;
    int cl = t & 63, rb = t >> 6;
#pragma unroll
    for (int j = 0; j < 16; j++) {
        int rl = rb + j * 4;
        tile[rl][cl] = ib[(size_t)(r0 + rl) * C + c0 + cl];
    }
    __syncthreads();
    int oc = t >> 2, q = t & 3;
    int g = q >> 1, sub = q & 1;
#pragma unroll
    for (int j = 0; j < 8; j++) {
        int x = sub * 8 + j;
        float v1 = tile[g * 32 + x][oc];
        float v2 = tile[g * 32 + x + 16][oc];
        _Float16 a = (_Float16)v1, b2 = (_Float16)v2;
        _Float16 la = (_Float16)(v1 - (float)a), lb = (_Float16)(v2 - (float)b2);
        size_t o = ob + (size_t)(c0 + oc) * R + r0 + g * 32 + 2 * x;
        half2_t hp; hp[0] = a; hp[1] = b2;
        half2_t lp; lp[0] = la; lp[1] = lb;
        *(half2_t*)&oh[o] = hp;
        *(half2_t*)&olo[o] = lp;
    }
}

// per-batch transpose: in [R,C] f32 (exact 0/1) -> out [C,R] u8
__global__ void transpose_u8(const float* __restrict__ in, unsigned char* __restrict__ out,
                             int R, int C) {
    int b = blockIdx.z;
    int c0 = blockIdx.x * 64, r0 = blockIdx.y * 64;
    const float* ib = in + (size_t)b * R * C;
    unsigned char* ob = out + (size_t)b * R * C;
    __shared__ float tile[64][65];
    int t = threadIdx.x;
    int cl = t & 63, rb = t >> 6;
#pragma unroll
    for (int j = 0; j < 16; j++) {
        int rl = rb + j * 4;
        tile[rl][cl] = ib[(size_t)(r0 + rl) * C + c0 + cl];
    }
    __syncthreads();
    int oc = t >> 2, q = t & 3;
    union { unsigned char b[16]; uint4 v; } u;
#pragma unroll
    for (int i = 0; i < 16; i++) u.b[i] = (unsigned char)tile[q * 16 + i][oc];
    size_t o = (size_t)(c0 + oc) * R + r0 + q * 16;
    *(uint4*)&ob[o] = u.v;
}

// ---------------------------------------------------------------------------
// NT GEMM with split-f16 emulated-fp32 operands (3 passes: hh + hl + lh)
template <bool A_SPLIT, bool B_SPLIT, bool HAS_BIAS, bool RELU, bool HAS_ADD,
          bool WRITE_F32, bool WRITE_SPLIT, bool B_BATCHED>
__global__ __launch_bounds__(256) void gemm_nt(
    const _Float16* __restrict__ Ah, const _Float16* __restrict__ Al,
    const _Float16* __restrict__ Bh, const _Float16* __restrict__ Bl,
    const float* __restrict__ bias, float bscale,
    const float* __restrict__ addsrc,
    float* __restrict__ Cf, _Float16* __restrict__ Chi, _Float16* __restrict__ Clo,
    int M, int Nn, int K) {
    const int bz = blockIdx.z;
    const int m0 = blockIdx.x * 128, n0 = blockIdx.y * 128;
    const int t = threadIdx.x, lane = t & 63, wid = t >> 6;
    const int wm = wid >> 1, wn = wid & 1;
    const size_t offA = (size_t)bz * M * K;
    const size_t offB = B_BATCHED ? (size_t)bz * Nn * K : (size_t)0;
    const _Float16* Abh = Ah + offA;
    const _Float16* Abl = A_SPLIT ? (Al + offA) : nullptr;
    const _Float16* Bbh = Bh + offB;
    const _Float16* Bbl = B_SPLIT ? (Bl + offB) : nullptr;

    __shared__ _Float16 sAh[128 * 32];
    __shared__ _Float16 sBh[128 * 32];
    __shared__ _Float16 sAl[A_SPLIT ? 128 * 32 : 1];
    __shared__ _Float16 sBl[B_SPLIT ? 128 * 32 : 1];

    f32x4 acc[4][4] = {};
    const int nk = K >> 5;

    auto gA = [&](const _Float16* base, int kt, int q) {
        return *(const uint4*)(base + (size_t)(m0 + (q >> 2)) * K + (kt << 5) + ((q & 3) << 3));
    };
    auto gB = [&](const _Float16* base, int kt, int q) {
        return *(const uint4*)(base + (size_t)(n0 + (q >> 2)) * K + (kt << 5) + ((q & 3) << 3));
    };

    uint4 rah0 = gA(Abh, 0, t), rah1 = gA(Abh, 0, t + 256);
    uint4 rbh0 = gB(Bbh, 0, t), rbh1 = gB(Bbh, 0, t + 256);
    uint4 ral0 = {}, ral1 = {}, rbl0 = {}, rbl1 = {};
    if (A_SPLIT) { ral0 = gA(Abl, 0, t); ral1 = gA(Abl, 0, t + 256); }
    if (B_SPLIT) { rbl0 = gB(Bbl, 0, t); rbl1 = gB(Bbl, 0, t + 256); }

    for (int kt = 0; kt < nk; ++kt) {
        __syncthreads();
        ((uint4*)sAh)[t] = rah0; ((uint4*)sAh)[t + 256] = rah1;
        ((uint4*)sBh)[t] = rbh0; ((uint4*)sBh)[t + 256] = rbh1;
        if (A_SPLIT) { ((uint4*)sAl)[t] = ral0; ((uint4*)sAl)[t + 256] = ral1; }
        if (B_SPLIT) { ((uint4*)sBl)[t] = rbl0; ((uint4*)sBl)[t + 256] = rbl1; }
        __syncthreads();
        if (kt + 1 < nk) {
            rah0 = gA(Abh, kt + 1, t); rah1 = gA(Abh, kt + 1, t + 256);
            rbh0 = gB(Bbh, kt + 1, t); rbh1 = gB(Bbh, kt + 1, t + 256);
            if (A_SPLIT) { ral0 = gA(Abl, kt + 1, t); ral1 = gA(Abl, kt + 1, t + 256); }
            if (B_SPLIT) { rbl0 = gB(Bbl, kt + 1, t); rbl1 = gB(Bbl, kt + 1, t + 256); }
        }
        half8 afh[4], bfh[4], afl[4], bfl[4];
#pragma unroll
        for (int mi = 0; mi < 4; mi++) {
            int off = (wm * 64 + mi * 16 + (lane & 15)) * 32 + ((lane >> 4) << 3);
            afh[mi] = *(const half8*)&sAh[off];
            if (A_SPLIT) afl[mi] = *(const half8*)&sAl[off];
        }
#pragma unroll
        for (int nj = 0; nj < 4; nj++) {
            int off = (wn * 64 + nj * 16 + (lane & 15)) * 32 + ((lane >> 4) << 3);
            bfh[nj] = *(const half8*)&sBh[off];
            if (B_SPLIT) bfl[nj] = *(const half8*)&sBl[off];
        }
#pragma unroll
        for (int mi = 0; mi < 4; mi++)
#pragma unroll
            for (int nj = 0; nj < 4; nj++) {
                acc[mi][nj] = __builtin_amdgcn_mfma_f32_16x16x32_f16(afh[mi], bfh[nj], acc[mi][nj], 0, 0, 0);
                if (B_SPLIT)
                    acc[mi][nj] = __builtin_amdgcn_mfma_f32_16x16x32_f16(afh[mi], bfl[nj], acc[mi][nj], 0, 0, 0);
                if (A_SPLIT)
                    acc[mi][nj] = __builtin_amdgcn_mfma_f32_16x16x32_f16(afl[mi], bfh[nj], acc[mi][nj], 0, 0, 0);
            }
    }

    const int rbase = (lane >> 4) * 4, cc = lane & 15;
#pragma unroll
    for (int mi = 0; mi < 4; mi++) {
#pragma unroll
        for (int nj = 0; nj < 4; nj++) {
            int gn = n0 + wn * 64 + nj * 16 + cc;
            float bv = HAS_BIAS ? bias[gn] * bscale : 0.f;
#pragma unroll
            for (int r = 0; r < 4; r++) {
                int gm = m0 + wm * 64 + mi * 16 + rbase + r;
                float v = acc[mi][nj][r];
                if (HAS_BIAS) v += bv;
                size_t off = ((size_t)bz * M + gm) * Nn + gn;
                if (HAS_ADD) v += addsrc[off];
                if (RELU) v = fmaxf(v, 0.f);
                if (WRITE_F32) Cf[off] = v;
                if (WRITE_SPLIT) {
                    _Float16 h = (_Float16)v;
                    Chi[off] = h;
                    Clo[off] = (_Float16)(v - (float)h);
                }
            }
        }
    }
}

// ---------------------------------------------------------------------------
// FUSED normalize + aggregation GEMM:
//   X[b][m][d] = (softmax-normalized P)[m][k] @ B[d][k]^T + addsrc, split-f16 out
// A-tile is computed on the fly from S + mask + per-m stats (c = max+ln(sum)):
//   P[m][k] = msk ? exp(s - c[m]) : exp(-c[m])
// TRANSA=true  (agg1): transposed staging, e-pair k-perm + XOR swizzle;
//   B (evT) pre-permuted to the same k-order (transpose_split_perm).
// TRANSA=false (agg2): direct row-major staging.
// 64x128 tile, 256 threads, 2x2 waves, wave tile 32x64 (champion geometry).
// R12 (WIN, 1359->1299): BK=64 via CH=2 side-by-side 32-col chunk buffers —
// halved the 2-barrier step count, amortizing the ~0.33 µs/step fixed cost.
// R13: extend the validated lever — CH = TRANSA ? 2 : 4 (agg2 BK=128,
// nk=16; agg1 keeps R12's proven CH=2 to bound VGPR in its transposed
// staging). agg2 LDS 80 KB -> exactly 2 blocks/CU (matches grid 2/CU);
// 4-deep chunk prefetch also puts ~400B/thread in flight per step.
template <bool TRANSA>
__global__ __launch_bounds__(256) void fused_agg(
    const float* __restrict__ S_, const unsigned char* __restrict__ Mk,
    const float2* __restrict__ st, const _Float16* __restrict__ Bh,
    const _Float16* __restrict__ Bl, const float* __restrict__ addsrc,
    _Float16* __restrict__ Xhi, _Float16* __restrict__ Xlo,
    int M, int K) {
    constexpr int CH = TRANSA ? 2 : 4;   // 32-wide k-chunks per step (BK = 32*CH)
    const int bz = blockIdx.z;
    const int m0 = blockIdx.x * 64, n0 = blockIdx.y * 128;
    const int t = threadIdx.x, lane = t & 63, wid = t >> 6;
    const int wm = wid >> 1, wn = wid & 1;   // 2x2 waves; wave tile 32(m) x 64(n)
    const float* Sb = S_ + (size_t)bz * EE * NN;
    const unsigned char* Mb = Mk + (size_t)bz * EE * NN;
    const float2* stb = st + (size_t)bz * M;
    const _Float16* Bbh = Bh + (size_t)bz * DD * K;
    const _Float16* Bbl = Bl + (size_t)bz * DD * K;

    __shared__ _Float16 sA[CH * 64 * 32];
    __shared__ _Float16 sBh[CH * 128 * 32];
    __shared__ _Float16 sBl[CH * 128 * 32];

    f32x4 acc[2][4] = {};
    const int nk = K / (32 * CH);   // agg1: 16, agg2: 16

    // hoisted per-thread softmax stats (c, e^-c)
    float stc[4], stem[4];
    if (TRANSA) {
        int ncol = (t & 15) * 4;
#pragma unroll
        for (int i = 0; i < 4; i++) {
            float2 v = stb[m0 + ncol + i];
            stc[i] = v.x; stem[i] = v.y;
        }
    } else {
#pragma unroll
        for (int p = 0; p < 2; p++) {
            float2 v = stb[m0 + (t >> 3) + p * 32];
            stc[p] = v.x; stem[p] = v.y;
        }
    }

    unsigned apack[CH][4];
    uint4 rbh0[CH], rbh1[CH], rbl0[CH], rbl1[CH];

    // c = global 32-wide k-chunk index; h2 = destination chunk buffer
    auto prefA = [&](int c, int h2) {
        if (TRANSA) {
            int r = t >> 4, ncol = (t & 15) * 4, e0 = c * 32;
            size_t rowoff = (size_t)(e0 + r) * NN + m0 + ncol;
            f32x4 s1 = *(const f32x4*)(Sb + rowoff);
            f32x4 s2 = *(const f32x4*)(Sb + rowoff + (size_t)16 * NN);
            unsigned a1 = *(const unsigned*)(Mb + rowoff);
            unsigned a2 = *(const unsigned*)(Mb + rowoff + (size_t)16 * NN);
#pragma unroll
            for (int i = 0; i < 4; i++) {
                float cc_ = stc[i], em = stem[i];
                float x1 = ((a1 >> (8 * i)) & 255u) ? __expf(s1[i] - cc_) : em;
                float x2 = ((a2 >> (8 * i)) & 255u) ? __expf(s2[i] - cc_) : em;
                apack[h2][i] = pk2((_Float16)x1, (_Float16)x2);
            }
        } else {
            int kc = (t & 7) * 4, rb = t >> 3;
#pragma unroll
            for (int p = 0; p < 2; p++) {
                size_t rowoff = (size_t)(m0 + rb + p * 32) * NN + c * 32 + kc;
                f32x4 s = *(const f32x4*)(Sb + rowoff);
                unsigned a = *(const unsigned*)(Mb + rowoff);
                float cc_ = stc[p], em = stem[p];
                _Float16 h0 = (_Float16)(((a) & 255u) ? __expf(s[0] - cc_) : em);
                _Float16 h1 = (_Float16)(((a >> 8) & 255u) ? __expf(s[1] - cc_) : em);
                _Float16 h2v = (_Float16)(((a >> 16) & 255u) ? __expf(s[2] - cc_) : em);
                _Float16 h3 = (_Float16)(((a >> 24) & 255u) ? __expf(s[3] - cc_) : em);
                apack[h2][2 * p] = pk2(h0, h1);
                apack[h2][2 * p + 1] = pk2(h2v, h3);
            }
        }
    };
    auto prefB = [&](int c, int h2) {
        auto g = [&](const _Float16* base, int q) {
            return *(const uint4*)(base + (size_t)(n0 + (q >> 2)) * K + c * 32 + (q & 3) * 8);
        };
        rbh0[h2] = g(Bbh, t); rbh1[h2] = g(Bbh, t + 256);
        rbl0[h2] = g(Bbl, t); rbl1[h2] = g(Bbl, t + 256);
    };
    auto storeAB = [&]() {
#pragma unroll
        for (int h2 = 0; h2 < CH; h2++) {
            unsigned* sAw = (unsigned*)(sA + h2 * (64 * 32));
            if (TRANSA) {
                int r = t >> 4, ncol = (t & 15) * 4;
#pragma unroll
                for (int i = 0; i < 4; i++) {
                    int n = ncol + i;
                    int cp = (r >> 2) ^ ((n >> 2) & 3);
                    sAw[n * 16 + cp * 4 + (r & 3)] = apack[h2][i];
                }
            } else {
                int kc = (t & 7) * 4, rb = t >> 3;
#pragma unroll
                for (int p = 0; p < 2; p++) {
                    unsigned* dst = (unsigned*)(sA + h2 * (64 * 32) + (rb + p * 32) * 32 + kc);
                    dst[0] = apack[h2][2 * p]; dst[1] = apack[h2][2 * p + 1];
                }
            }
            ((uint4*)(sBh + h2 * (128 * 32)))[t] = rbh0[h2];
            ((uint4*)(sBh + h2 * (128 * 32)))[t + 256] = rbh1[h2];
            ((uint4*)(sBl + h2 * (128 * 32)))[t] = rbl0[h2];
            ((uint4*)(sBl + h2 * (128 * 32)))[t + 256] = rbl1[h2];
        }
    };

#pragma unroll
    for (int h2 = 0; h2 < CH; h2++) { prefA(h2, h2); prefB(h2, h2); }

    const int l4 = lane & 15, hh = lane >> 4;
    const int cswz = TRANSA ? (hh ^ ((l4 >> 2) & 3)) : hh;

    for (int kt = 0; kt < nk; ++kt) {
        __syncthreads();
        storeAB();
        __syncthreads();
        if (kt + 1 < nk) {
#pragma unroll
            for (int h2 = 0; h2 < CH; h2++) {
                prefA(CH * (kt + 1) + h2, h2);
                prefB(CH * (kt + 1) + h2, h2);
            }
        }
#pragma unroll
        for (int ks = 0; ks < CH; ks++) {
            half8 af[2], bfh[4], bfl[4];
#pragma unroll
            for (int mi = 0; mi < 2; mi++)
                af[mi] = *(const half8*)&sA[ks * (64 * 32) + (wm * 32 + mi * 16 + l4) * 32 + cswz * 8];
#pragma unroll
            for (int nj = 0; nj < 4; nj++) {
                int off = ks * (128 * 32) + (wn * 64 + nj * 16 + l4) * 32 + hh * 8;
                bfh[nj] = *(const half8*)&sBh[off];
                bfl[nj] = *(const half8*)&sBl[off];
            }
#pragma unroll
            for (int mi = 0; mi < 2; mi++)
#pragma unroll
                for (int nj = 0; nj < 4; nj++) {
                    acc[mi][nj] = __builtin_amdgcn_mfma_f32_16x16x32_f16(af[mi], bfh[nj], acc[mi][nj], 0, 0, 0);
                    acc[mi][nj] = __builtin_amdgcn_mfma_f32_16x16x32_f16(af[mi], bfl[nj], acc[mi][nj], 0, 0, 0);
                }
        }
    }

    const int rbase = (lane >> 4) * 4, cc = lane & 15;
#pragma unroll
    for (int mi = 0; mi < 2; mi++) {
#pragma unroll
        for (int nj = 0; nj < 4; nj++) {
            int gn = n0 + wn * 64 + nj * 16 + cc;
#pragma unroll
            for (int r = 0; r < 4; r++) {
                int gm = m0 + wm * 32 + mi * 16 + rbase + r;
                size_t off = ((size_t)bz * M + gm) * DD + gn;
                float v = acc[mi][nj][r] + addsrc[off];
                _Float16 h = (_Float16)v;
                Xhi[off] = h;
                Xlo[off] = (_Float16)(v - (float)h);
            }
        }
    }
}

// ---------------------------------------------------------------------------
// stats: ONE pass over S computes online-softmax (max, sum) partials for BOTH
// directions. Masked entries contribute x=0 (reference multiplies score*mask).
__global__ __launch_bounds__(256) void stats(const float* __restrict__ S_,
                                             const unsigned char* __restrict__ m1,
                                             const unsigned char* __restrict__ m2t,
                                             float2* __restrict__ d1p,
                                             float2* __restrict__ d2p) {
    int b = blockIdx.z, e0 = blockIdx.y * 64, n0 = blockIdx.x * 256;
    int t = threadIdx.x, lane = t & 63, w = t >> 6;
    size_t base = ((size_t)b * EE + e0) * NN + n0;

    f32x4 xs[16];
    unsigned int am[16], cm[16];
#pragma unroll
    for (int j = 0; j < 16; j++) {
        size_t off = base + (size_t)(w * 16 + j) * NN + lane * 4;
        float4 s = *(const float4*)(S_ + off);
        xs[j][0] = s.x; xs[j][1] = s.y; xs[j][2] = s.z; xs[j][3] = s.w;
        am[j] = *(const unsigned int*)(m1 + off);
        cm[j] = *(const unsigned int*)(m2t + off);
    }

    // ---- column stats (E-softmax, m1 mask)
    float cmx[4], csm[4];
#pragma unroll
    for (int i = 0; i < 4; i++) {
        float mx = ((am[0] >> (8 * i)) & 0xffu) ? xs[0][i] : 0.f;
#pragma unroll
        for (int j = 1; j < 16; j++) {
            float xe = ((am[j] >> (8 * i)) & 0xffu) ? xs[j][i] : 0.f;
            mx = fmaxf(mx, xe);
        }
        float sm = 0.f;
#pragma unroll
        for (int j = 0; j < 16; j++) {
            float xe = ((am[j] >> (8 * i)) & 0xffu) ? xs[j][i] : 0.f;
            sm += __expf(xe - mx);
        }
        cmx[i] = mx; csm[i] = sm;
    }
    __shared__ float rm[4][256], rs[4][256];
#pragma unroll
    for (int i = 0; i < 4; i++) { rm[w][lane * 4 + i] = cmx[i]; rs[w][lane * 4 + i] = csm[i]; }
    __syncthreads();
    {
        float M0 = rm[0][t], S0 = rs[0][t];
#pragma unroll
        for (int ww = 1; ww < 4; ww++) pmerge(M0, S0, rm[ww][t], rs[ww][t]);
        d1p[(size_t)blockIdx.y * (BB * NN) + (size_t)b * NN + n0 + t] = make_float2(M0, S0);
    }

    // ---- row stats (N-softmax, m2t mask)
#pragma unroll
    for (int j = 0; j < 16; j++) {
        float x0 = ((cm[j]) & 0xffu) ? xs[j][0] : 0.f;
        float x1 = ((cm[j] >> 8) & 0xffu) ? xs[j][1] : 0.f;
        float x2 = ((cm[j] >> 16) & 0xffu) ? xs[j][2] : 0.f;
        float x3 = ((cm[j] >> 24) & 0xffu) ? xs[j][3] : 0.f;
        float mx = fmaxf(fmaxf(x0, x1), fmaxf(x2, x3));
#pragma unroll
        for (int off = 1; off < 64; off <<= 1) mx = fmaxf(mx, __shfl_xor(mx, off, 64));
        float sm = __expf(x0 - mx) + __expf(x1 - mx) + __expf(x2 - mx) + __expf(x3 - mx);
#pragma unroll
        for (int off = 1; off < 64; off <<= 1) sm += __shfl_xor(sm, off, 64);
        if (lane == 0)
            d2p[(size_t)blockIdx.x * (BB * EE) + (size_t)b * EE + e0 + w * 16 + j] = make_float2(mx, sm);
    }
}

// merge partials -> (c = m + ln(sum), e^-c) for the fused-agg staging
__global__ void reduce_dens(const float2* __restrict__ d1p, const float2* __restrict__ d2p,
                            float2* __restrict__ d1, float2* __restrict__ d2) {
    int i = blockIdx.x * 256 + threadIdx.x;
    if (i < BB * NN) {
        float2 v = d1p[i];
        float m = v.x, s = v.y;
#pragma unroll
        for (int k = 1; k < 16; k++) {
            float2 u = d1p[(size_t)k * (BB * NN) + i];
            pmerge(m, s, u.x, u.y);
        }
        float c = m + __logf(s);
        d1[i] = make_float2(c, __expf(-c));
    } else {
        int j = i - BB * NN;
        if (j < BB * EE) {
            float2 v = d2p[j];
            float m = v.x, s = v.y;
#pragma unroll
            for (int k = 1; k < 8; k++) {
                float2 u = d2p[(size_t)k * (BB * EE) + j];
                pmerge(m, s, u.x, u.y);
            }
            float c = m + __logf(s);
            d2[j] = make_float2(c, __expf(-c));
        }
    }
}

// ---------------------------------------------------------------------------
extern "C" void kernel_launch(void* const* d_in, const int* in_sizes, int n_in,
                              void* d_out, int out_size, void* d_ws, size_t ws_size,
                              hipStream_t stream) {
    const float* evid   = (const float*)d_in[0];   // [B,E,D]
    const float* enti   = (const float*)d_in[1];   // [B,N,D]
    const float* ev2ent = (const float*)d_in[2];   // [B,E,N]
    const float* ent2ev = (const float*)d_in[3];   // [B,N,E]
    const float* w_w    = (const float*)d_in[4];   // [L,D,D]
    const float* w_b    = (const float*)d_in[5];   // [L,D]
    const float* wa_w   = (const float*)d_in[6];   // [L,D,D]
    const float* wa_b   = (const float*)d_in[7];   // [L,D]
    float* out_ent = (float*)d_out;                           // [B,N,D]
    float* out_ev  = out_ent + (size_t)BB * NN * DD;          // [B,E,D]

    char* p = (char*)d_ws;
    auto alloc = [&](size_t bytes) {
        char* r = p;
        p += (bytes + 255) & ~(size_t)255;
        return (void*)r;
    };
    const size_t nED = (size_t)BB * EE * DD, nND = (size_t)BB * NN * DD;
    const size_t nEN = (size_t)BB * EE * NN, nW = (size_t)LL * DD * DD;
    _Float16* Whi  = (_Float16*)alloc(nW * 2);
    _Float16* Wlo  = (_Float16*)alloc(nW * 2);
    _Float16* Wahi = (_Float16*)alloc(nW * 2);
    _Float16* Walo = (_Float16*)alloc(nW * 2);
    _Float16* evh  = (_Float16*)alloc(nED * 2);
    _Float16* evl  = (_Float16*)alloc(nED * 2);
    _Float16* enth = (_Float16*)alloc(nND * 2);
    _Float16* entl = (_Float16*)alloc(nND * 2);
    _Float16* evTh = (_Float16*)alloc(nED * 2);
    _Float16* evTl = (_Float16*)alloc(nED * 2);
    _Float16* entTh= (_Float16*)alloc(nND * 2);
    _Float16* entTl= (_Float16*)alloc(nND * 2);
    _Float16* peh  = (_Float16*)alloc(nED * 2);
    _Float16* pel  = (_Float16*)alloc(nED * 2);
    _Float16* pnh  = (_Float16*)alloc(nND * 2);
    _Float16* pnl  = (_Float16*)alloc(nND * 2);
    float*    S    = (float*)alloc(nEN * 4);
    unsigned char* m1  = (unsigned char*)alloc(nEN);
    unsigned char* m2t = (unsigned char*)alloc(nEN);
    float* evS  = (float*)alloc(nED * 4);
    float* entS = (float*)alloc(nND * 4);
    float2* d1p = (float2*)alloc((size_t)16 * BB * NN * 8);
    float2* d2p = (float2*)alloc((size_t)8 * BB * EE * 8);
    float2* d1  = (float2*)alloc((size_t)BB * NN * 8);
    float2* d2  = (float2*)alloc((size_t)BB * EE * 8);
    if ((size_t)(p - (char*)d_ws) > ws_size) return;  // workspace too small — bail
    _Float16* Xenth = pnh; _Float16* Xentl = pnl;  // alias: pn consumed before Xent written
    _Float16* Xevh  = peh; _Float16* Xevl  = pel;  // alias: pe consumed before Xev written

    // ---- setup ----
    split_cast<<<2048, 256, 0, stream>>>(wa_w, Wahi, Walo, nW);
    split_cast<<<2048, 256, 0, stream>>>(w_w, Whi, Wlo, nW);
    split_cast<<<2048, 256, 0, stream>>>(evid, evh, evl, nED);
    split_cast<<<2048, 256, 0, stream>>>(enti, enth, entl, nND);
    cast_u8<<<2048, 256, 0, stream>>>(ev2ent, m1, nEN);
    transpose_u8<<<dim3(EE / 64, NN / 64, BB), 256, 0, stream>>>(ent2ev, m2t, NN, EE);
    transpose_split_perm<<<dim3(DD / 64, EE / 64, BB), 256, 0, stream>>>(evid, evTh, evTl, EE, DD);
    hipMemcpyAsync(evS, evid, nED * 4, hipMemcpyDeviceToDevice, stream);
    hipMemcpyAsync(entS, enti, nND * 4, hipMemcpyDeviceToDevice, stream);

    for (int i = 0; i < LL; i++) {
        const _Float16* Wih  = Whi + (size_t)i * DD * DD;
        const _Float16* Wil  = Wlo + (size_t)i * DD * DD;
        const _Float16* Waih = Wahi + (size_t)i * DD * DD;
        const _Float16* Wail = Walo + (size_t)i * DD * DD;
        const float* bi  = w_b + i * DD;
        const float* bai = wa_b + i * DD;

        // 1. pe = ev @ Watt^T + bias  (split out)
        gemm_nt<true, true, true, false, false, false, true, false>
            <<<dim3(EE / 128, DD / 128, BB), 256, 0, stream>>>(
                evh, evl, Waih, Wail, bai, 1.f, nullptr, nullptr, peh, pel, EE, DD, DD);
        // 2. pn = ent @ Watt^T + bias
        gemm_nt<true, true, true, false, false, false, true, false>
            <<<dim3(NN / 128, DD / 128, BB), 256, 0, stream>>>(
                enth, entl, Waih, Wail, bai, 1.f, nullptr, nullptr, pnh, pnl, NN, DD, DD);
        // 3. S = pe @ pn^T  (f32)
        gemm_nt<true, true, false, false, false, true, false, true>
            <<<dim3(EE / 128, NN / 128, BB), 256, 0, stream>>>(
                peh, pel, pnh, pnl, nullptr, 0.f, nullptr, S, nullptr, nullptr, EE, NN, DD);
        // 4. exact online-softmax stats for both directions, one pass over S
        stats<<<dim3(NN / 256, EE / 64, BB), 256, 0, stream>>>(S, m1, m2t, d1p, d2p);
        reduce_dens<<<(BB * NN + BB * EE + 255) / 256, 256, 0, stream>>>(d1p, d2p, d1, d2);
        // 5. Xent = split(softmaxE(S*m1)^T @ evT^T + ent_old)   [fused norm+agg]
        fused_agg<true><<<dim3(NN / 64, 2, BB), 256, 0, stream>>>(
            S, m1, d1, evTh, evTl, entS, Xenth, Xentl, NN, EE);
        // 6. ent_new = relu(Xent @ W^T + 2b)  (f32 state/out + split)
        float* entDst = (i == LL - 1) ? out_ent : entS;
        gemm_nt<true, true, true, true, false, true, true, false>
            <<<dim3(NN / 128, DD / 128, BB), 256, 0, stream>>>(
                Xenth, Xentl, Wih, Wil, bi, 2.f, nullptr, entDst, enth, entl, NN, DD, DD);
        // 7. entT = transpose(ent_new) (split, linear) — feeds agg2 this layer
        transpose_split<<<dim3(DD / 64, NN / 64, BB), 256, 0, stream>>>(entDst, entTh, entTl, NN, DD);
        // 8. Xev = split(softmaxN(S*m2t) @ entT^T + ev_old)     [fused norm+agg]
        fused_agg<false><<<dim3(EE / 64, 2, BB), 256, 0, stream>>>(
            S, m2t, d2, entTh, entTl, evS, Xevh, Xevl, EE, NN);
        // 9. ev_new = relu(Xev @ W^T + 2b)
        float* evDst = (i == LL - 1) ? out_ev : evS;
        gemm_nt<true, true, true, true, false, true, true, false>
            <<<dim3(EE / 128, DD / 128, BB), 256, 0, stream>>>(
                Xevh, Xevl, Wih, Wil, bi, 2.f, nullptr, evDst, evh, evl, EE, DD, DD);
        // 10. evT (permuted) for next layer
        if (i < LL - 1)
            transpose_split_perm<<<dim3(DD / 64, EE / 64, BB), 256, 0, stream>>>(evS, evTh, evTl, EE, DD);
    }
}